// Round 1
// baseline (18047.913 us; speedup 1.0000x reference)
//
#include <hip/hip_runtime.h>
#include <hip/hip_bf16.h>
#include <cmath>

#define SEQ 1024
#define EMBED 1280
#define HEADS 16
#define HD 80
#define MLP_DIM 5120
#define HIDDEN 3584
#define QKV3 3840
#define PATCH_DIMS 1176
#define DEPTH 8
#define MSEQ 256
#define MDIM 5120

// ---------------- reductions ----------------
__device__ inline float waveReduceSum(float v) {
#pragma unroll
  for (int o = 32; o; o >>= 1) v += __shfl_xor(v, o);
  return v;
}
__device__ inline float waveReduceMax(float v) {
#pragma unroll
  for (int o = 32; o; o >>= 1) v = fmaxf(v, __shfl_xor(v, o));
  return v;
}

// ---------------- RoPE tables ----------------
// cos/sin tables, 40 entries per token (cols 40..79 are duplicates of 0..39).
__global__ void rope_tables_kernel(const int* gh_p, const int* gw_p,
                                   float* __restrict__ cosT, float* __restrict__ sinT) {
  int s = blockIdx.x;
  int j = threadIdx.x;
  if (j >= 40) return;
  int gh = *gh_p, gw = *gw_p;
  int f = s % (gh * gw);
  int d0 = f & 1;
  int b = (f >> 1) & 1;
  int rest = f >> 2;
  int W2 = gw >> 1;
  int c = rest % W2;
  int a = rest / W2;
  int hpos = a * 2 + b;
  int wpos = c * 2 + d0;
  int jp = j % 20;
  // inv = 10000^(-(2*jp)/40)
  float inv = powf(10000.0f, -(2.0f * (float)jp) / 40.0f);
  float val = (float)(j < 20 ? hpos : wpos) * inv;
  cosT[s * 40 + j] = cosf(val);
  sinT[s * 40 + j] = sinf(val);
}

// apply RoPE in-place to q and k inside qkv buffer (SEQ x 3 x HEADS x HD)
__global__ __launch_bounds__(256) void rope_apply_kernel(float* __restrict__ qkv,
                                                         const float* __restrict__ cosT,
                                                         const float* __restrict__ sinT) {
  int idx = blockIdx.x * 256 + threadIdx.x;  // over SEQ*HEADS*40
  int d = idx % 40;
  int h = (idx / 40) % HEADS;
  int s = idx / (40 * HEADS);
  if (s >= SEQ) return;
  float cs = cosT[s * 40 + d];
  float sn = sinT[s * 40 + d];
#pragma unroll
  for (int c = 0; c < 2; ++c) {
    float* base = qkv + ((size_t)s * 3 + c) * EMBED + h * HD;
    float x0 = base[d];
    float x1 = base[d + 40];
    base[d] = x0 * cs - x1 * sn;
    base[d + 40] = x1 * cs + x0 * sn;
  }
}

// ---------------- LayerNorm (1280 cols) ----------------
__global__ __launch_bounds__(256) void layernorm1280(const float* __restrict__ x,
                                                     const float* __restrict__ g,
                                                     const float* __restrict__ b,
                                                     float* __restrict__ y) {
  const float* row = x + (size_t)blockIdx.x * EMBED;
  float* out = y + (size_t)blockIdx.x * EMBED;
  int tid = threadIdx.x;
  __shared__ float r0[4], r1[4];
  float v[5];
  float s = 0.f, sq = 0.f;
#pragma unroll
  for (int i = 0; i < 5; ++i) {
    v[i] = row[tid + (i << 8)];
    s += v[i];
    sq += v[i] * v[i];
  }
  float ws1 = waveReduceSum(s);
  float ws2 = waveReduceSum(sq);
  int lane = tid & 63, wid = tid >> 6;
  if (!lane) { r0[wid] = ws1; r1[wid] = ws2; }
  __syncthreads();
  s = r0[0] + r0[1] + r0[2] + r0[3];
  sq = r1[0] + r1[1] + r1[2] + r1[3];
  float mean = s * (1.0f / EMBED);
  float var = sq * (1.0f / EMBED) - mean * mean;
  float rstd = rsqrtf(var + 1e-6f);
#pragma unroll
  for (int i = 0; i < 5; ++i) {
    int col = tid + (i << 8);
    out[col] = (v[i] - mean) * rstd * g[col] + b[col];
  }
}

// ---------------- softmax over rows of 1024 ----------------
__global__ __launch_bounds__(256) void softmax1024(float* __restrict__ S) {
  float* row = S + (size_t)blockIdx.x * 1024;
  int tid = threadIdx.x;
  __shared__ float rm[4], rs[4];
  float v[4];
  float mx = -1e30f;
#pragma unroll
  for (int i = 0; i < 4; ++i) {
    v[i] = row[tid + (i << 8)];
    mx = fmaxf(mx, v[i]);
  }
  float wm = waveReduceMax(mx);
  int lane = tid & 63, wid = tid >> 6;
  if (!lane) rm[wid] = wm;
  __syncthreads();
  mx = fmaxf(fmaxf(rm[0], rm[1]), fmaxf(rm[2], rm[3]));
  float sum = 0.f;
#pragma unroll
  for (int i = 0; i < 4; ++i) {
    v[i] = __expf(v[i] - mx);
    sum += v[i];
  }
  float ws = waveReduceSum(sum);
  if (!lane) rs[wid] = ws;
  __syncthreads();
  sum = rs[0] + rs[1] + rs[2] + rs[3];
  float inv = 1.0f / sum;
#pragma unroll
  for (int i = 0; i < 4; ++i) row[tid + (i << 8)] = v[i] * inv;
}

// ---------------- GEMM NN: C = A(MxK) * B(KxN) (+bias)(+epilogue) ----------------
// epi: 0 = none, 1 = swish(x*sigmoid(1.702x)), 2 = tanh-gelu, 3 = add residual (res, same ldc)
__global__ __launch_bounds__(256) void gemm_nn(
    const float* __restrict__ A, int lda, long long sA,
    const float* __restrict__ B, int ldb, long long sB,
    const float* __restrict__ bias,
    const float* __restrict__ res,
    float* __restrict__ C, int ldc, long long sC,
    int M, int N, int K, int epi) {
  __shared__ float As[16][66];
  __shared__ float Bs[16][66];
  int bz = blockIdx.z;
  A += (long long)bz * sA;
  B += (long long)bz * sB;
  C += (long long)bz * sC;
  int bm = blockIdx.y << 6, bn = blockIdx.x << 6;
  int tid = threadIdx.x, tx = tid & 15, ty = tid >> 4;
  float acc[4][4] = {};
  for (int k0 = 0; k0 < K; k0 += 16) {
#pragma unroll
    for (int i = 0; i < 4; ++i) {
      int idx = (tid << 2) + i;
      int m = idx >> 4, k = idx & 15;
      float v = 0.f;
      int gm = bm + m, gk = k0 + k;
      if (gm < M && gk < K) v = A[(long long)gm * lda + gk];
      As[k][m] = v;
    }
#pragma unroll
    for (int i = 0; i < 4; ++i) {
      int idx = tid + (i << 8);
      int k = idx >> 6, n = idx & 63;
      float v = 0.f;
      int gk = k0 + k, gn = bn + n;
      if (gk < K && gn < N) v = B[(long long)gk * ldb + gn];
      Bs[k][n] = v;
    }
    __syncthreads();
#pragma unroll
    for (int kk = 0; kk < 16; ++kk) {
      float2 a0 = *(const float2*)&As[kk][ty << 2];
      float2 a1 = *(const float2*)&As[kk][(ty << 2) + 2];
      float2 b0 = *(const float2*)&Bs[kk][tx << 2];
      float2 b1 = *(const float2*)&Bs[kk][(tx << 2) + 2];
      float av[4] = {a0.x, a0.y, a1.x, a1.y};
      float bv[4] = {b0.x, b0.y, b1.x, b1.y};
#pragma unroll
      for (int r = 0; r < 4; ++r)
#pragma unroll
        for (int c = 0; c < 4; ++c) acc[r][c] = fmaf(av[r], bv[c], acc[r][c]);
    }
    __syncthreads();
  }
#pragma unroll
  for (int r = 0; r < 4; ++r) {
    int m = bm + (ty << 2) + r;
    if (m >= M) continue;
#pragma unroll
    for (int c = 0; c < 4; ++c) {
      int n = bn + (tx << 2) + c;
      if (n >= N) continue;
      float v = acc[r][c];
      if (bias) v += bias[n];
      if (epi == 1) {
        v = v / (1.0f + __expf(-1.702f * v));
      } else if (epi == 2) {
        float t = v;
        v = 0.5f * t * (1.0f + tanhf(0.79788456080286535588f * (t + 0.044715f * t * t * t)));
      } else if (epi == 3) {
        v += res[(long long)m * ldc + n];
      }
      C[(long long)m * ldc + n] = v;
    }
  }
}

// ---------------- GEMM NT: C = scale * A(MxK) * B(NxK)^T ----------------
__global__ __launch_bounds__(256) void gemm_nt(
    const float* __restrict__ A, int lda, long long sA,
    const float* __restrict__ B, int ldb, long long sB,
    float* __restrict__ C, int ldc, long long sC,
    int M, int N, int K, float scale) {
  __shared__ float As[16][66];
  __shared__ float Bs[16][66];
  int bz = blockIdx.z;
  A += (long long)bz * sA;
  B += (long long)bz * sB;
  C += (long long)bz * sC;
  int bm = blockIdx.y << 6, bn = blockIdx.x << 6;
  int tid = threadIdx.x, tx = tid & 15, ty = tid >> 4;
  float acc[4][4] = {};
  for (int k0 = 0; k0 < K; k0 += 16) {
#pragma unroll
    for (int i = 0; i < 4; ++i) {
      int idx = (tid << 2) + i;
      int m = idx >> 4, k = idx & 15;
      float v = 0.f;
      int gm = bm + m, gk = k0 + k;
      if (gm < M && gk < K) v = A[(long long)gm * lda + gk];
      As[k][m] = v;
    }
#pragma unroll
    for (int i = 0; i < 4; ++i) {
      int idx = (tid << 2) + i;
      int n = idx >> 4, k = idx & 15;
      float v = 0.f;
      int gn = bn + n, gk = k0 + k;
      if (gn < N && gk < K) v = B[(long long)gn * ldb + gk];
      Bs[k][n] = v;
    }
    __syncthreads();
#pragma unroll
    for (int kk = 0; kk < 16; ++kk) {
      float2 a0 = *(const float2*)&As[kk][ty << 2];
      float2 a1 = *(const float2*)&As[kk][(ty << 2) + 2];
      float2 b0 = *(const float2*)&Bs[kk][tx << 2];
      float2 b1 = *(const float2*)&Bs[kk][(tx << 2) + 2];
      float av[4] = {a0.x, a0.y, a1.x, a1.y};
      float bv[4] = {b0.x, b0.y, b1.x, b1.y};
#pragma unroll
      for (int r = 0; r < 4; ++r)
#pragma unroll
        for (int c = 0; c < 4; ++c) acc[r][c] = fmaf(av[r], bv[c], acc[r][c]);
    }
    __syncthreads();
  }
#pragma unroll
  for (int r = 0; r < 4; ++r) {
    int m = bm + (ty << 2) + r;
    if (m >= M) continue;
#pragma unroll
    for (int c = 0; c < 4; ++c) {
      int n = bn + (tx << 2) + c;
      if (n >= N) continue;
      C[(long long)m * ldc + n] = acc[r][c] * scale;
    }
  }
}

extern "C" void kernel_launch(void* const* d_in, const int* in_sizes, int n_in,
                              void* d_out, int out_size, void* d_ws, size_t ws_size,
                              hipStream_t stream) {
  const float* x = (const float*)d_in[0];
  const float* patch_w = (const float*)d_in[1];
  const float* ln1_g = (const float*)d_in[2];
  const float* ln1_b = (const float*)d_in[3];
  const float* qkv_w = (const float*)d_in[4];
  const float* qkv_b = (const float*)d_in[5];
  const float* proj_w = (const float*)d_in[6];
  const float* proj_b = (const float*)d_in[7];
  const float* ln2_g = (const float*)d_in[8];
  const float* ln2_b = (const float*)d_in[9];
  const float* fc1_w = (const float*)d_in[10];
  const float* fc1_b = (const float*)d_in[11];
  const float* fc2_w = (const float*)d_in[12];
  const float* fc2_b = (const float*)d_in[13];
  const float* mln_g = (const float*)d_in[14];
  const float* mln_b = (const float*)d_in[15];
  const float* mfc1_w = (const float*)d_in[16];
  const float* mfc1_b = (const float*)d_in[17];
  const float* mfc2_w = (const float*)d_in[18];
  const float* mfc2_b = (const float*)d_in[19];
  const int* grid_h = (const int*)d_in[21];
  const int* grid_w = (const int*)d_in[22];

  float* ws = (float*)d_ws;
  float* h = ws;                       // 1310720
  float* y = h + 1310720;              // 1310720
  float* qkv = y + 1310720;            // 3932160
  float* o = qkv + 3932160;            // 1310720
  float* u = o + 1310720;              // 5242880
  float* m1 = u + 5242880;             // 1310720
  float* cosT = m1 + 1310720;          // 40960
  float* sinT = cosT + 40960;          // 40960
  float* sc = sinT + 40960;            // 16777216 (16 x 1024 x 1024)

  const float scale = 1.0f / sqrtf(80.0f);
  dim3 blk(256);

  rope_tables_kernel<<<SEQ, 64, 0, stream>>>(grid_h, grid_w, cosT, sinT);

  // patch embed: h = x @ patch_w
  gemm_nn<<<dim3(EMBED / 64, SEQ / 64, 1), blk, 0, stream>>>(
      x, PATCH_DIMS, 0, patch_w, EMBED, 0, nullptr, nullptr,
      h, EMBED, 0, SEQ, EMBED, PATCH_DIMS, 0);

  for (int l = 0; l < DEPTH; ++l) {
    layernorm1280<<<SEQ, 256, 0, stream>>>(h, ln1_g + l * EMBED, ln1_b + l * EMBED, y);
    gemm_nn<<<dim3(QKV3 / 64, SEQ / 64, 1), blk, 0, stream>>>(
        y, EMBED, 0, qkv_w + (long long)l * EMBED * QKV3, QKV3, 0,
        qkv_b + l * QKV3, nullptr, qkv, QKV3, 0, SEQ, QKV3, EMBED, 0);
    rope_apply_kernel<<<(SEQ * HEADS * 40) / 256, 256, 0, stream>>>(qkv, cosT, sinT);
    // scores[h] = scale * q @ k^T
    gemm_nt<<<dim3(16, 16, HEADS), blk, 0, stream>>>(
        qkv, QKV3, HD, qkv + EMBED, QKV3, HD,
        sc, SEQ, 1024LL * 1024, SEQ, SEQ, HD, scale);
    softmax1024<<<HEADS * SEQ, 256, 0, stream>>>(sc);
    // o[h] = scores[h] @ v[h]
    gemm_nn<<<dim3(2, 16, HEADS), blk, 0, stream>>>(
        sc, SEQ, 1024LL * 1024, qkv + 2 * EMBED, QKV3, HD,
        nullptr, nullptr, o, EMBED, HD, SEQ, HD, SEQ, 0);
    // h = h + o @ proj_w + proj_b
    gemm_nn<<<dim3(EMBED / 64, SEQ / 64, 1), blk, 0, stream>>>(
        o, EMBED, 0, proj_w + (long long)l * EMBED * EMBED, EMBED, 0,
        proj_b + l * EMBED, h, h, EMBED, 0, SEQ, EMBED, EMBED, 3);
    layernorm1280<<<SEQ, 256, 0, stream>>>(h, ln2_g + l * EMBED, ln2_b + l * EMBED, y);
    // u = swish(y @ fc1_w + fc1_b)
    gemm_nn<<<dim3(MLP_DIM / 64, SEQ / 64, 1), blk, 0, stream>>>(
        y, EMBED, 0, fc1_w + (long long)l * EMBED * MLP_DIM, MLP_DIM, 0,
        fc1_b + l * MLP_DIM, nullptr, u, MLP_DIM, 0, SEQ, MLP_DIM, EMBED, 1);
    // h = h + u @ fc2_w + fc2_b
    gemm_nn<<<dim3(EMBED / 64, SEQ / 64, 1), blk, 0, stream>>>(
        u, MLP_DIM, 0, fc2_w + (long long)l * MLP_DIM * EMBED, EMBED, 0,
        fc2_b + l * EMBED, h, h, EMBED, 0, SEQ, EMBED, MLP_DIM, 3);
  }

  // merger
  layernorm1280<<<SEQ, 256, 0, stream>>>(h, mln_g, mln_b, y);
  // y viewed as (256, 5120) row-major
  gemm_nn<<<dim3(MDIM / 64, MSEQ / 64, 1), blk, 0, stream>>>(
      y, MDIM, 0, mfc1_w, MDIM, 0, mfc1_b, nullptr,
      m1, MDIM, 0, MSEQ, MDIM, MDIM, 2);
  gemm_nn<<<dim3(HIDDEN / 64, MSEQ / 64, 1), blk, 0, stream>>>(
      m1, MDIM, 0, mfc2_w, HIDDEN, 0, mfc2_b, nullptr,
      (float*)d_out, HIDDEN, 0, MSEQ, HIDDEN, MDIM, 0);
}

// Round 2
// 3896.131 us; speedup vs baseline: 4.6323x; 4.6323x over previous
//
#include <hip/hip_runtime.h>
#include <hip/hip_bf16.h>
#include <cmath>

#define SEQ 1024
#define EMBED 1280
#define HEADS 16
#define HD 80
#define HDP 96
#define HDV 128
#define MLP_DIM 5120
#define HIDDEN 3584
#define QKV3 3840
#define PATCH_DIMS 1176
#define PATCH_PAD 1184
#define DEPTH 8
#define MSEQ 256
#define MDIM 5120

typedef short short8 __attribute__((ext_vector_type(8)));
typedef float f32x4 __attribute__((ext_vector_type(4)));

#define GLOAD16(g, l)                                                          \
  __builtin_amdgcn_global_load_lds(                                            \
      (const __attribute__((address_space(1))) void*)(g),                      \
      (__attribute__((address_space(3))) void*)(l), 16, 0, 0)

__device__ __forceinline__ float bf2f(unsigned short u) {
  union { unsigned int i; float f; } x;
  x.i = ((unsigned int)u) << 16;
  return x.f;
}
__device__ __forceinline__ unsigned short f2bf(float f) {
  union { float f; unsigned int i; } x;
  x.f = f;
  unsigned int r = x.i + 0x7fffu + ((x.i >> 16) & 1u);
  return (unsigned short)(r >> 16);
}

// ---------------- reductions ----------------
__device__ inline float waveReduceSum(float v) {
#pragma unroll
  for (int o = 32; o; o >>= 1) v += __shfl_xor(v, o);
  return v;
}
__device__ inline float waveReduceMax(float v) {
#pragma unroll
  for (int o = 32; o; o >>= 1) v = fmaxf(v, __shfl_xor(v, o));
  return v;
}

// ---------------- RoPE tables ----------------
__global__ void rope_tables_kernel(const int* gh_p, const int* gw_p,
                                   float* __restrict__ cosT, float* __restrict__ sinT) {
  int s = blockIdx.x;
  int j = threadIdx.x;
  if (j >= 40) return;
  int gh = *gh_p, gw = *gw_p;
  int f = s % (gh * gw);
  int d0 = f & 1;
  int b = (f >> 1) & 1;
  int rest = f >> 2;
  int W2 = gw >> 1;
  int c = rest % W2;
  int a = rest / W2;
  int hpos = a * 2 + b;
  int wpos = c * 2 + d0;
  int jp = j % 20;
  float inv = powf(10000.0f, -(2.0f * (float)jp) / 40.0f);
  float val = (float)(j < 20 ? hpos : wpos) * inv;
  cosT[s * 40 + j] = cosf(val);
  sinT[s * 40 + j] = sinf(val);
}

// apply RoPE in-place to q and k inside qkv buffer (SEQ x 3 x HEADS x HD), f32
__global__ __launch_bounds__(256) void rope_apply_kernel(float* __restrict__ qkv,
                                                         const float* __restrict__ cosT,
                                                         const float* __restrict__ sinT) {
  int idx = blockIdx.x * 256 + threadIdx.x;
  int d = idx % 40;
  int h = (idx / 40) % HEADS;
  int s = idx / (40 * HEADS);
  if (s >= SEQ) return;
  float cs = cosT[s * 40 + d];
  float sn = sinT[s * 40 + d];
#pragma unroll
  for (int c = 0; c < 2; ++c) {
    float* base = qkv + ((size_t)s * 3 + c) * EMBED + h * HD;
    float x0 = base[d];
    float x1 = base[d + 40];
    base[d] = x0 * cs - x1 * sn;
    base[d + 40] = x1 * cs + x0 * sn;
  }
}

// ---------------- LayerNorm 1280 : f32 in -> bf16 out ----------------
__global__ __launch_bounds__(256) void layernorm1280(const float* __restrict__ x,
                                                     const float* __restrict__ g,
                                                     const float* __restrict__ b,
                                                     unsigned short* __restrict__ y) {
  const float* row = x + (size_t)blockIdx.x * EMBED;
  unsigned short* out = y + (size_t)blockIdx.x * EMBED;
  int tid = threadIdx.x;
  __shared__ float r0[4], r1[4];
  float v[5];
  float s = 0.f, sq = 0.f;
#pragma unroll
  for (int i = 0; i < 5; ++i) {
    v[i] = row[tid + (i << 8)];
    s += v[i];
    sq += v[i] * v[i];
  }
  float ws1 = waveReduceSum(s);
  float ws2 = waveReduceSum(sq);
  int lane = tid & 63, wid = tid >> 6;
  if (!lane) { r0[wid] = ws1; r1[wid] = ws2; }
  __syncthreads();
  s = r0[0] + r0[1] + r0[2] + r0[3];
  sq = r1[0] + r1[1] + r1[2] + r1[3];
  float mean = s * (1.0f / EMBED);
  float var = sq * (1.0f / EMBED) - mean * mean;
  float rstd = rsqrtf(var + 1e-6f);
#pragma unroll
  for (int i = 0; i < 5; ++i) {
    int col = tid + (i << 8);
    out[col] = f2bf((v[i] - mean) * rstd * g[col] + b[col]);
  }
}

// ---------------- softmax over rows of 1024 bf16, in-place ----------------
typedef short short4v __attribute__((ext_vector_type(4)));
__global__ __launch_bounds__(256) void softmax1024(unsigned short* __restrict__ S) {
  unsigned short* row = S + (size_t)blockIdx.x * 1024;
  int tid = threadIdx.x;
  __shared__ float rm[4], rs[4];
  short4v raw = *(const short4v*)&row[tid << 2];
  float v[4];
  float mx = -1e30f;
#pragma unroll
  for (int i = 0; i < 4; ++i) {
    v[i] = bf2f((unsigned short)raw[i]);
    mx = fmaxf(mx, v[i]);
  }
  float wm = waveReduceMax(mx);
  int lane = tid & 63, wid = tid >> 6;
  if (!lane) rm[wid] = wm;
  __syncthreads();
  mx = fmaxf(fmaxf(rm[0], rm[1]), fmaxf(rm[2], rm[3]));
  float sum = 0.f;
#pragma unroll
  for (int i = 0; i < 4; ++i) {
    v[i] = __expf(v[i] - mx);
    sum += v[i];
  }
  float ws = waveReduceSum(sum);
  if (!lane) rs[wid] = ws;
  __syncthreads();
  sum = rs[0] + rs[1] + rs[2] + rs[3];
  float inv = 1.0f / sum;
  short4v o;
#pragma unroll
  for (int i = 0; i < 4; ++i) o[i] = (short)f2bf(v[i] * inv);
  *(short4v*)&row[tid << 2] = o;
}

// ---------------- weight transpose+convert: f32 [Ksrc][N] -> bf16 [N][Kpad] ----------------
__global__ __launch_bounds__(256) void transpose_w(const float* __restrict__ W,
                                                   unsigned short* __restrict__ Wt,
                                                   int Ksrc, int Kpad, int N) {
  __shared__ float t[32][33];
  int k0 = blockIdx.x * 32, n0 = blockIdx.y * 32;
  int tx = threadIdx.x & 31, ty = threadIdx.x >> 5;  // 32 x 8
#pragma unroll
  for (int i = 0; i < 32; i += 8) {
    int k = k0 + ty + i;
    t[ty + i][tx] = (k < Ksrc) ? W[(long long)k * N + n0 + tx] : 0.f;
  }
  __syncthreads();
#pragma unroll
  for (int i = 0; i < 32; i += 8) {
    Wt[(long long)(n0 + ty + i) * Kpad + k0 + tx] = f2bf(t[tx][ty + i]);
  }
}

// ---------------- x convert: f32 [1024][1176] -> bf16 [1024][1184] ----------------
__global__ __launch_bounds__(256) void convert_x(const float* __restrict__ x,
                                                 unsigned short* __restrict__ xb) {
  int idx = blockIdx.x * 256 + threadIdx.x;
  if (idx >= SEQ * PATCH_PAD) return;
  int j = idx % PATCH_PAD, s = idx / PATCH_PAD;
  xb[idx] = (j < PATCH_DIMS) ? f2bf(x[(long long)s * PATCH_DIMS + j]) : 0;
}

// ---------------- qkv f32 -> padded bf16 q,k (s-major) ----------------
__global__ __launch_bounds__(256) void pack_qk(const float* __restrict__ qkv,
                                               unsigned short* __restrict__ qb,
                                               unsigned short* __restrict__ kb) {
  int idx = blockIdx.x * 256 + threadIdx.x;  // SEQ*HEADS*HDP
  int d = idx % HDP;
  int h = (idx / HDP) % HEADS;
  int s = idx / (HDP * HEADS);
  if (s >= SEQ) return;
  long long o = ((long long)h * SEQ + s) * HDP + d;
  if (d < HD) {
    long long src = (long long)s * QKV3 + h * HD + d;
    qb[o] = f2bf(qkv[src]);
    kb[o] = f2bf(qkv[src + EMBED]);
  } else {
    qb[o] = 0;
    kb[o] = 0;
  }
}

// ---------------- qkv f32 -> v transposed bf16 [h][d(128)][s] ----------------
__global__ __launch_bounds__(256) void pack_v(const float* __restrict__ qkv,
                                              unsigned short* __restrict__ vb) {
  int idx = blockIdx.x * 256 + threadIdx.x;  // HEADS*HDV*SEQ
  int s = idx & (SEQ - 1);
  int d = (idx >> 10) & (HDV - 1);
  int h = idx >> 17;
  if (h >= HEADS) return;
  float val = (d < HD) ? qkv[(long long)s * QKV3 + 2 * EMBED + h * HD + d] : 0.f;
  vb[((long long)h * HDV + d) * SEQ + s] = f2bf(val);
}

// ---------------- bf16 MFMA GEMM: C = A(MxK) * Bt(NxK)^T ----------------
// mode: 0 plain f32 | 1 bias f32 | 2 bias+residual f32 | 3 bias+swish bf16
//       4 bias+gelu bf16 | 5 scale bf16 | 6 plain bf16
__global__ __launch_bounds__(256) void gemm_bt(
    const unsigned short* __restrict__ A, int lda, long long sA,
    const unsigned short* __restrict__ Bt, int ldb, long long sB,
    const float* __restrict__ bias,
    const float* __restrict__ res,
    void* __restrict__ Cout, int ldc, long long sC,
    int M, int N, int K, int mode, float scale) {
  __shared__ short As[128 * 32];
  __shared__ short Bs[128 * 32];
  int bz = blockIdx.z;
  A += (long long)bz * sA;
  Bt += (long long)bz * sB;
  int bm = blockIdx.y << 7, bn = blockIdx.x << 7;
  int tid = threadIdx.x;
  int lane = tid & 63, wid = tid >> 6;
  int wr = wid >> 1, wc = wid & 1;
  f32x4 acc[4][4] = {};

  int arow = (wid << 4) + (lane >> 2);  // 0..63
  int kblk = (lane & 3) << 3;           // 0,8,16,24
  const unsigned short* ga = A + (long long)(bm + arow) * lda + kblk;
  const unsigned short* gb = Bt + (long long)(bn + arow) * ldb + kblk;
  short* la = &As[arow * 32 + kblk];
  short* lb = &Bs[arow * 32 + kblk];
  long long stepA = 64LL * lda, stepB = 64LL * ldb;

  int l15 = lane & 15, kb8 = (lane >> 4) << 3;
  int rowA = (wr << 6) + l15;
  int rowB = (wc << 6) + l15;

  for (int k0 = 0; k0 < K; k0 += 32) {
    __syncthreads();
    GLOAD16(ga, la);
    GLOAD16(ga + stepA, la + 64 * 32);
    GLOAD16(gb, lb);
    GLOAD16(gb + stepB, lb + 64 * 32);
    ga += 32;
    gb += 32;
    __syncthreads();
    short8 af[4], bfr[4];
#pragma unroll
    for (int m = 0; m < 4; ++m)
      af[m] = *(const short8*)&As[(rowA + (m << 4)) * 32 + kb8];
#pragma unroll
    for (int n = 0; n < 4; ++n)
      bfr[n] = *(const short8*)&Bs[(rowB + (n << 4)) * 32 + kb8];
#pragma unroll
    for (int m = 0; m < 4; ++m)
#pragma unroll
      for (int n = 0; n < 4; ++n)
        acc[m][n] = __builtin_amdgcn_mfma_f32_16x16x32_bf16(af[m], bfr[n], acc[m][n], 0, 0, 0);
  }

  int lg = lane >> 4;
  float* Cf = (float*)Cout + (long long)bz * sC;
  unsigned short* Cb = (unsigned short*)Cout + (long long)bz * sC;
#pragma unroll
  for (int m = 0; m < 4; ++m) {
    int row0 = bm + (wr << 6) + (m << 4) + (lg << 2);
#pragma unroll
    for (int n = 0; n < 4; ++n) {
      int col = bn + (wc << 6) + (n << 4) + l15;
      if (col >= N) continue;
      float bval = bias ? bias[col] : 0.f;
#pragma unroll
      for (int r = 0; r < 4; ++r) {
        int row = row0 + r;
        float v = acc[m][n][r];
        long long ci = (long long)row * ldc + col;
        if (mode == 0) {
          Cf[ci] = v;
        } else if (mode == 1) {
          Cf[ci] = v + bval;
        } else if (mode == 2) {
          Cf[ci] = v + bval + res[ci];
        } else if (mode == 3) {
          v += bval;
          Cb[ci] = f2bf(v / (1.0f + __expf(-1.702f * v)));
        } else if (mode == 4) {
          v += bval;
          Cb[ci] = f2bf(0.5f * v * (1.0f + tanhf(0.79788456080286535588f *
                                                 (v + 0.044715f * v * v * v))));
        } else if (mode == 5) {
          Cb[ci] = f2bf(v * scale);
        } else {
          Cb[ci] = f2bf(v);
        }
      }
    }
  }
}

extern "C" void kernel_launch(void* const* d_in, const int* in_sizes, int n_in,
                              void* d_out, int out_size, void* d_ws, size_t ws_size,
                              hipStream_t stream) {
  const float* x = (const float*)d_in[0];
  const float* patch_w = (const float*)d_in[1];
  const float* ln1_g = (const float*)d_in[2];
  const float* ln1_b = (const float*)d_in[3];
  const float* qkv_w = (const float*)d_in[4];
  const float* qkv_b = (const float*)d_in[5];
  const float* proj_w = (const float*)d_in[6];
  const float* proj_b = (const float*)d_in[7];
  const float* ln2_g = (const float*)d_in[8];
  const float* ln2_b = (const float*)d_in[9];
  const float* fc1_w = (const float*)d_in[10];
  const float* fc1_b = (const float*)d_in[11];
  const float* fc2_w = (const float*)d_in[12];
  const float* fc2_b = (const float*)d_in[13];
  const float* mln_g = (const float*)d_in[14];
  const float* mln_b = (const float*)d_in[15];
  const float* mfc1_w = (const float*)d_in[16];
  const float* mfc1_b = (const float*)d_in[17];
  const float* mfc2_w = (const float*)d_in[18];
  const float* mfc2_b = (const float*)d_in[19];
  const int* grid_h = (const int*)d_in[21];
  const int* grid_w = (const int*)d_in[22];

  char* ws = (char*)d_ws;
  float* h = (float*)ws;                       ws += (size_t)SEQ * EMBED * 4;        // 5.24MB
  float* qkv = (float*)ws;                     ws += (size_t)SEQ * QKV3 * 4;         // 15.7MB
  float* cosT = (float*)ws;                    ws += (size_t)SEQ * 40 * 4;
  float* sinT = (float*)ws;                    ws += (size_t)SEQ * 40 * 4;
  unsigned short* y = (unsigned short*)ws;     ws += (size_t)SEQ * EMBED * 2;        // 2.62MB
  unsigned short* ob = (unsigned short*)ws;    ws += (size_t)SEQ * EMBED * 2;        // 2.62MB
  unsigned short* m1b = (unsigned short*)ws;   ws += (size_t)MSEQ * MDIM * 2;        // 2.62MB
  unsigned short* qb = (unsigned short*)ws;    ws += (size_t)HEADS * SEQ * HDP * 2;  // 3.15MB
  unsigned short* kb = (unsigned short*)ws;    ws += (size_t)HEADS * SEQ * HDP * 2;  // 3.15MB
  unsigned short* vb = (unsigned short*)ws;    ws += (size_t)HEADS * HDV * SEQ * 2;  // 4.19MB
  unsigned short* wt = (unsigned short*)ws;    ws += (size_t)MDIM * MDIM * 2;        // 52.4MB
  // union region: sc (32MB bf16) / u (10.5MB bf16) / xb (2.4MB) — disjoint lifetimes
  unsigned short* sc = (unsigned short*)ws;
  unsigned short* u = (unsigned short*)ws;
  unsigned short* xb = (unsigned short*)ws;

  const float scale = 1.0f / sqrtf(80.0f);
  dim3 blk(256);

  rope_tables_kernel<<<SEQ, 64, 0, stream>>>(grid_h, grid_w, cosT, sinT);

  // ---- patch embed: h = x @ patch_w  (f32 out, no bias) ----
  convert_x<<<(SEQ * PATCH_PAD + 255) / 256, blk, 0, stream>>>(x, xb);
  transpose_w<<<dim3(PATCH_PAD / 32, EMBED / 32), blk, 0, stream>>>(
      patch_w, wt, PATCH_DIMS, PATCH_PAD, EMBED);
  gemm_bt<<<dim3(EMBED / 128, SEQ / 128, 1), blk, 0, stream>>>(
      xb, PATCH_PAD, 0, wt, PATCH_PAD, 0, nullptr, nullptr,
      h, EMBED, 0, SEQ, EMBED, PATCH_PAD, 0, 1.f);

  for (int l = 0; l < DEPTH; ++l) {
    // qkv = LN1(h) @ qkv_w + qkv_b   (f32 out)
    layernorm1280<<<SEQ, 256, 0, stream>>>(h, ln1_g + l * EMBED, ln1_b + l * EMBED, y);
    transpose_w<<<dim3(EMBED / 32, QKV3 / 32), blk, 0, stream>>>(
        qkv_w + (long long)l * EMBED * QKV3, wt, EMBED, EMBED, QKV3);
    gemm_bt<<<dim3(QKV3 / 128, SEQ / 128, 1), blk, 0, stream>>>(
        y, EMBED, 0, wt, EMBED, 0, qkv_b + l * QKV3, nullptr,
        qkv, QKV3, 0, SEQ, QKV3, EMBED, 1, 1.f);
    rope_apply_kernel<<<(SEQ * HEADS * 40) / 256, blk, 0, stream>>>(qkv, cosT, sinT);
    pack_qk<<<(SEQ * HEADS * HDP) / 256, blk, 0, stream>>>(qkv, qb, kb);
    pack_v<<<(HEADS * HDV * SEQ) / 256, blk, 0, stream>>>(qkv, vb);
    // scores = scale * q @ k^T  (bf16 out)
    gemm_bt<<<dim3(SEQ / 128, SEQ / 128, HEADS), blk, 0, stream>>>(
        qb, HDP, (long long)SEQ * HDP, kb, HDP, (long long)SEQ * HDP,
        nullptr, nullptr, sc, SEQ, (long long)SEQ * SEQ,
        SEQ, SEQ, HDP, 5, scale);
    softmax1024<<<HEADS * SEQ, 256, 0, stream>>>(sc);
    // o = P @ v  (bf16 out into ob[s][h*80+d])
    gemm_bt<<<dim3(1, SEQ / 128, HEADS), blk, 0, stream>>>(
        sc, SEQ, (long long)SEQ * SEQ, vb, SEQ, (long long)HDV * SEQ,
        nullptr, nullptr, ob, EMBED, HD,
        SEQ, HD, SEQ, 6, 1.f);
    // h += o @ proj_w + proj_b
    transpose_w<<<dim3(EMBED / 32, EMBED / 32), blk, 0, stream>>>(
        proj_w + (long long)l * EMBED * EMBED, wt, EMBED, EMBED, EMBED);
    gemm_bt<<<dim3(EMBED / 128, SEQ / 128, 1), blk, 0, stream>>>(
        ob, EMBED, 0, wt, EMBED, 0, proj_b + l * EMBED, h,
        h, EMBED, 0, SEQ, EMBED, EMBED, 2, 1.f);
    // u = swish(LN2(h) @ fc1_w + fc1_b)  (bf16 out)
    layernorm1280<<<SEQ, 256, 0, stream>>>(h, ln2_g + l * EMBED, ln2_b + l * EMBED, y);
    transpose_w<<<dim3(EMBED / 32, MLP_DIM / 32), blk, 0, stream>>>(
        fc1_w + (long long)l * EMBED * MLP_DIM, wt, EMBED, EMBED, MLP_DIM);
    gemm_bt<<<dim3(MLP_DIM / 128, SEQ / 128, 1), blk, 0, stream>>>(
        y, EMBED, 0, wt, EMBED, 0, fc1_b + l * MLP_DIM, nullptr,
        u, MLP_DIM, 0, SEQ, MLP_DIM, EMBED, 3, 1.f);
    // h += u @ fc2_w + fc2_b
    transpose_w<<<dim3(MLP_DIM / 32, EMBED / 32), blk, 0, stream>>>(
        fc2_w + (long long)l * MLP_DIM * EMBED, wt, MLP_DIM, MLP_DIM, EMBED);
    gemm_bt<<<dim3(EMBED / 128, SEQ / 128, 1), blk, 0, stream>>>(
        u, MLP_DIM, 0, wt, MLP_DIM, 0, fc2_b + l * EMBED, h,
        h, EMBED, 0, SEQ, EMBED, MLP_DIM, 2, 1.f);
  }

  // ---- merger ----
  layernorm1280<<<SEQ, 256, 0, stream>>>(h, mln_g, mln_b, y);
  // y viewed as bf16 (256, 5120)
  transpose_w<<<dim3(MDIM / 32, MDIM / 32), blk, 0, stream>>>(
      mfc1_w, wt, MDIM, MDIM, MDIM);
  gemm_bt<<<dim3(MDIM / 128, MSEQ / 128, 1), blk, 0, stream>>>(
      y, MDIM, 0, wt, MDIM, 0, mfc1_b, nullptr,
      m1b, MDIM, 0, MSEQ, MDIM, MDIM, 4, 1.f);
  transpose_w<<<dim3(MDIM / 32, HIDDEN / 32), blk, 0, stream>>>(
      mfc2_w, wt, MDIM, MDIM, HIDDEN);
  gemm_bt<<<dim3(HIDDEN / 128, MSEQ / 128, 1), blk, 0, stream>>>(
      m1b, MDIM, 0, wt, MDIM, 0, mfc2_b, nullptr,
      (float*)d_out, HIDDEN, 0, MSEQ, HIDDEN, MDIM, 1, 1.f);
}

// Round 3
// 3441.140 us; speedup vs baseline: 5.2447x; 1.1322x over previous
//
#include <hip/hip_runtime.h>
#include <hip/hip_bf16.h>
#include <cmath>

#define SEQ 1024
#define EMBED 1280
#define HEADS 16
#define HD 80
#define HDP 96
#define MLP_DIM 5120
#define HIDDEN 3584
#define QKV3 3840
#define PATCH_DIMS 1176
#define PATCH_PAD 1184
#define DEPTH 8
#define MSEQ 256
#define MDIM 5120

typedef short short8 __attribute__((ext_vector_type(8)));
typedef short short4v __attribute__((ext_vector_type(4)));
typedef float f32x4 __attribute__((ext_vector_type(4)));

#define GLOAD16(g, l)                                                          \
  __builtin_amdgcn_global_load_lds(                                            \
      (const __attribute__((address_space(1))) void*)(g),                      \
      (__attribute__((address_space(3))) void*)(l), 16, 0, 0)

__device__ __forceinline__ float bf2f(unsigned short u) {
  union { unsigned int i; float f; } x;
  x.i = ((unsigned int)u) << 16;
  return x.f;
}
__device__ __forceinline__ unsigned short f2bf(float f) {
  union { float f; unsigned int i; } x;
  x.f = f;
  unsigned int r = x.i + 0x7fffu + ((x.i >> 16) & 1u);
  return (unsigned short)(r >> 16);
}

// ---------------- reductions ----------------
__device__ inline float waveReduceSum(float v) {
#pragma unroll
  for (int o = 32; o; o >>= 1) v += __shfl_xor(v, o);
  return v;
}

// ---------------- RoPE tables ----------------
__global__ void rope_tables_kernel(const int* gh_p, const int* gw_p,
                                   float* __restrict__ cosT, float* __restrict__ sinT) {
  int s = blockIdx.x;
  int j = threadIdx.x;
  if (j >= 40) return;
  int gh = *gh_p, gw = *gw_p;
  int f = s % (gh * gw);
  int d0 = f & 1;
  int b = (f >> 1) & 1;
  int rest = f >> 2;
  int W2 = gw >> 1;
  int c = rest % W2;
  int a = rest / W2;
  int hpos = a * 2 + b;
  int wpos = c * 2 + d0;
  int jp = j % 20;
  float inv = powf(10000.0f, -(2.0f * (float)jp) / 40.0f);
  float val = (float)(j < 20 ? hpos : wpos) * inv;
  cosT[s * 40 + j] = cosf(val);
  sinT[s * 40 + j] = sinf(val);
}

// ---------------- LayerNorm 1280 : f32 in -> bf16 out ----------------
__global__ __launch_bounds__(256) void layernorm1280(const float* __restrict__ x,
                                                     const float* __restrict__ g,
                                                     const float* __restrict__ b,
                                                     unsigned short* __restrict__ y) {
  const float* row = x + (size_t)blockIdx.x * EMBED;
  unsigned short* out = y + (size_t)blockIdx.x * EMBED;
  int tid = threadIdx.x;
  __shared__ float r0[4], r1[4];
  float v[5];
  float s = 0.f, sq = 0.f;
#pragma unroll
  for (int i = 0; i < 5; ++i) {
    v[i] = row[tid + (i << 8)];
    s += v[i];
    sq += v[i] * v[i];
  }
  float ws1 = waveReduceSum(s);
  float ws2 = waveReduceSum(sq);
  int lane = tid & 63, wid = tid >> 6;
  if (!lane) { r0[wid] = ws1; r1[wid] = ws2; }
  __syncthreads();
  s = r0[0] + r0[1] + r0[2] + r0[3];
  sq = r1[0] + r1[1] + r1[2] + r1[3];
  float mean = s * (1.0f / EMBED);
  float var = sq * (1.0f / EMBED) - mean * mean;
  float rstd = rsqrtf(var + 1e-6f);
#pragma unroll
  for (int i = 0; i < 5; ++i) {
    int col = tid + (i << 8);
    out[col] = f2bf((v[i] - mean) * rstd * g[col] + b[col]);
  }
}

// ---------------- weight transpose+convert: f32 [Ksrc][N] -> bf16 [N][Kpad] ----------------
__global__ __launch_bounds__(256) void transpose_w(const float* __restrict__ W,
                                                   unsigned short* __restrict__ Wt,
                                                   int Ksrc, int Kpad, int N) {
  __shared__ float t[32][33];
  int k0 = blockIdx.x * 32, n0 = blockIdx.y * 32;
  int tx = threadIdx.x & 31, ty = threadIdx.x >> 5;  // 32 x 8
#pragma unroll
  for (int i = 0; i < 32; i += 8) {
    int k = k0 + ty + i;
    t[ty + i][tx] = (k < Ksrc) ? W[(long long)k * N + n0 + tx] : 0.f;
  }
  __syncthreads();
#pragma unroll
  for (int i = 0; i < 32; i += 8) {
    Wt[(long long)(n0 + ty + i) * Kpad + k0 + tx] = f2bf(t[tx][ty + i]);
  }
}

// ---------------- x convert: f32 [1024][1176] -> bf16 [1024][1184] ----------------
__global__ __launch_bounds__(256) void convert_x(const float* __restrict__ x,
                                                 unsigned short* __restrict__ xb) {
  int idx = blockIdx.x * 256 + threadIdx.x;
  if (idx >= SEQ * PATCH_PAD) return;
  int j = idx % PATCH_PAD, s = idx / PATCH_PAD;
  xb[idx] = (j < PATCH_DIMS) ? f2bf(x[(long long)s * PATCH_DIMS + j]) : 0;
}

// ---------------- fused RoPE + pack q,k: f32 qkv -> bf16 qb,kb [h][s][96] ----------------
__global__ __launch_bounds__(256) void pack_qk_rope(
    const float* __restrict__ qkv,
    const float* __restrict__ cosT, const float* __restrict__ sinT,
    unsigned short* __restrict__ qb, unsigned short* __restrict__ kb,
    float qscale) {
  int idx = blockIdx.x * 256 + threadIdx.x;  // SEQ*HEADS*48
  int d = idx % 48;
  int hh = (idx / 48) % HEADS;
  int s = idx / (48 * HEADS);
  if (s >= SEQ) return;
  size_t ob = ((size_t)hh * SEQ + s) * HDP;
  if (d >= 40) {
    int p = 80 + (d - 40) * 2;
    qb[ob + p] = 0; qb[ob + p + 1] = 0;
    kb[ob + p] = 0; kb[ob + p + 1] = 0;
    return;
  }
  float cs = cosT[s * 40 + d], sn = sinT[s * 40 + d];
  size_t src = (size_t)s * QKV3 + hh * HD + d;
  float q0 = qkv[src], q1 = qkv[src + 40];
  float k0 = qkv[src + EMBED], k1 = qkv[src + EMBED + 40];
  qb[ob + d] = f2bf((q0 * cs - q1 * sn) * qscale);
  qb[ob + d + 40] = f2bf((q1 * cs + q0 * sn) * qscale);
  kb[ob + d] = f2bf(k0 * cs - k1 * sn);
  kb[ob + d + 40] = f2bf(k1 * cs + k0 * sn);
}

// ---------------- pack V transposed: f32 qkv -> bf16 vb [h][80][1024] ----------------
__global__ __launch_bounds__(256) void pack_v(const float* __restrict__ qkv,
                                              unsigned short* __restrict__ vb) {
  __shared__ unsigned short t[80][72];
  int hh = blockIdx.y, s0 = blockIdx.x << 6;
  int tid = threadIdx.x;
  int s = tid >> 2, c0 = (tid & 3) * 20;
  const float* src = qkv + (size_t)(s0 + s) * QKV3 + 2 * EMBED + hh * HD + c0;
#pragma unroll
  for (int j = 0; j < 20; ++j) t[c0 + j][s] = f2bf(src[j]);
  __syncthreads();
  unsigned short* dst = vb + (size_t)hh * 80 * SEQ + s0;
#pragma unroll
  for (int i = 0; i < 3; ++i) {
    int c = tid + (i << 8);
    if (c < 640) {
      int dr = c >> 3, col = (c & 7) << 3;
      *(short8*)&dst[(size_t)dr * SEQ + col] = *(const short8*)&t[dr][col];
    }
  }
}

// ---------------- fused flash attention ----------------
// qb,kb: [h][1024][96] bf16 (q pre-scaled), vb: [h][80][1024] bf16
// out ob: [1024][1280] bf16 at col h*80+d
__global__ __launch_bounds__(256) void flash_attn(
    const unsigned short* __restrict__ qb,
    const unsigned short* __restrict__ kb,
    const unsigned short* __restrict__ vb,
    unsigned short* __restrict__ ob) {
  __shared__ short Ks[64 * 104];
  __shared__ short Vs[80 * 72];
  __shared__ short Ps[4 * 16 * 72];
  int h = blockIdx.y, q0 = blockIdx.x << 6;
  int tid = threadIdx.x, lane = tid & 63, wid = tid >> 6;
  int l15 = lane & 15, lg = lane >> 4;
  int kb8 = lg << 3;

  // Q fragments (B operand): 3 chunks of K=32 over d=96, loop-invariant
  short8 qf[3];
  {
    const unsigned short* qrow = qb + ((size_t)h * SEQ + q0 + (wid << 4) + l15) * HDP;
#pragma unroll
    for (int dc = 0; dc < 3; ++dc) qf[dc] = *(const short8*)&qrow[dc * 32 + kb8];
  }

  f32x4 o_acc[5] = {};
  float m_run = -1e30f, l_run = 0.f;
  short* myP = &Ps[(wid * 16 + l15) * 72];

  for (int t = 0; t < 16; ++t) {
    int kv0 = t << 6;
    __syncthreads();
    // stage K tile (64 x 96) and V^T tile (80 x 64)
    {
      const unsigned short* gk = kb + ((size_t)h * SEQ + kv0) * HDP;
#pragma unroll
      for (int i = 0; i < 3; ++i) {
        int c = tid + (i << 8);  // 0..767
        int row = c / 12, col = (c % 12) << 3;
        *(short8*)&Ks[row * 104 + col] = *(const short8*)&gk[row * HDP + col];
      }
      const unsigned short* gv = vb + (size_t)h * 80 * SEQ + kv0;
#pragma unroll
      for (int i = 0; i < 3; ++i) {
        int c = tid + (i << 8);
        if (c < 640) {
          int row = c >> 3, col = (c & 7) << 3;
          *(short8*)&Vs[row * 72 + col] = *(const short8*)&gv[(size_t)row * SEQ + col];
        }
      }
    }
    __syncthreads();

    // S^T[kv 64][q 16] = K @ Q^T
    f32x4 s[4] = {};
#pragma unroll
    for (int ks = 0; ks < 4; ++ks) {
#pragma unroll
      for (int dc = 0; dc < 3; ++dc) {
        short8 kf = *(const short8*)&Ks[(ks * 16 + l15) * 104 + dc * 32 + kb8];
        s[ks] = __builtin_amdgcn_mfma_f32_16x16x32_bf16(kf, qf[dc], s[ks], 0, 0, 0);
      }
    }

    // online softmax: per lane, 16 kv-values of q-row l15
    float mloc = -1e30f;
#pragma unroll
    for (int ks = 0; ks < 4; ++ks)
#pragma unroll
      for (int r = 0; r < 4; ++r) mloc = fmaxf(mloc, s[ks][r]);
    mloc = fmaxf(mloc, __shfl_xor(mloc, 16));
    mloc = fmaxf(mloc, __shfl_xor(mloc, 32));
    float m_new = fmaxf(m_run, mloc);
    float alpha = __expf(m_run - m_new);
    float psum = 0.f;
#pragma unroll
    for (int ks = 0; ks < 4; ++ks) {
      short4v pk;
#pragma unroll
      for (int r = 0; r < 4; ++r) {
        float p = __expf(s[ks][r] - m_new);
        psum += p;
        pk[r] = (short)f2bf(p);
      }
      *(short4v*)&myP[ks * 16 + (lg << 2)] = pk;  // Ps[q][kv]
    }
    psum += __shfl_xor(psum, 16);
    psum += __shfl_xor(psum, 32);
    l_run = l_run * alpha + psum;
    m_run = m_new;
#pragma unroll
    for (int dt = 0; dt < 5; ++dt)
#pragma unroll
      for (int r = 0; r < 4; ++r) o_acc[dt][r] *= alpha;

    // O^T[d 80][q 16] += V^T @ P^T
#pragma unroll
    for (int dt = 0; dt < 5; ++dt) {
#pragma unroll
      for (int kc = 0; kc < 2; ++kc) {
        short8 vf = *(const short8*)&Vs[(dt * 16 + l15) * 72 + kc * 32 + kb8];
        short8 pf = *(const short8*)&myP[kc * 32 + kb8];
        o_acc[dt] = __builtin_amdgcn_mfma_f32_16x16x32_bf16(vf, pf, o_acc[dt], 0, 0, 0);
      }
    }
  }

  float inv = 1.0f / l_run;
  unsigned short* orow = ob + (size_t)(q0 + (wid << 4) + l15) * EMBED + h * HD;
#pragma unroll
  for (int dt = 0; dt < 5; ++dt) {
    short4v ov;
#pragma unroll
    for (int r = 0; r < 4; ++r) ov[r] = (short)f2bf(o_acc[dt][r] * inv);
    *(short4v*)&orow[dt * 16 + (lg << 2)] = ov;
  }
}

// ---------------- bf16 MFMA GEMM: C = A(MxK) * Bt(NxK)^T ----------------
// mode: 0 plain f32 | 1 bias f32 | 2 bias+residual f32 | 3 bias+swish bf16
//       4 bias+gelu bf16
__global__ __launch_bounds__(256) void gemm_bt(
    const unsigned short* __restrict__ A, int lda, long long sA,
    const unsigned short* __restrict__ Bt, int ldb, long long sB,
    const float* __restrict__ bias,
    const float* __restrict__ res,
    void* __restrict__ Cout, int ldc, long long sC,
    int M, int N, int K, int mode, float scale) {
  __shared__ short As[128 * 32];
  __shared__ short Bs[128 * 32];
  int bz = blockIdx.z;
  A += (long long)bz * sA;
  Bt += (long long)bz * sB;
  int bm = blockIdx.y << 7, bn = blockIdx.x << 7;
  int tid = threadIdx.x;
  int lane = tid & 63, wid = tid >> 6;
  int wr = wid >> 1, wc = wid & 1;
  f32x4 acc[4][4] = {};

  int arow = (wid << 4) + (lane >> 2);
  int kblk = (lane & 3) << 3;
  const unsigned short* ga = A + (long long)(bm + arow) * lda + kblk;
  const unsigned short* gb = Bt + (long long)(bn + arow) * ldb + kblk;
  short* la = &As[arow * 32 + kblk];
  short* lb = &Bs[arow * 32 + kblk];
  long long stepA = 64LL * lda, stepB = 64LL * ldb;

  int l15 = lane & 15, kb8 = (lane >> 4) << 3;
  int rowA = (wr << 6) + l15;
  int rowB = (wc << 6) + l15;

  for (int k0 = 0; k0 < K; k0 += 32) {
    __syncthreads();
    GLOAD16(ga, la);
    GLOAD16(ga + stepA, la + 64 * 32);
    GLOAD16(gb, lb);
    GLOAD16(gb + stepB, lb + 64 * 32);
    ga += 32;
    gb += 32;
    __syncthreads();
    short8 af[4], bfr[4];
#pragma unroll
    for (int m = 0; m < 4; ++m)
      af[m] = *(const short8*)&As[(rowA + (m << 4)) * 32 + kb8];
#pragma unroll
    for (int n = 0; n < 4; ++n)
      bfr[n] = *(const short8*)&Bs[(rowB + (n << 4)) * 32 + kb8];
#pragma unroll
    for (int m = 0; m < 4; ++m)
#pragma unroll
      for (int n = 0; n < 4; ++n)
        acc[m][n] = __builtin_amdgcn_mfma_f32_16x16x32_bf16(af[m], bfr[n], acc[m][n], 0, 0, 0);
  }

  int lg = lane >> 4;
  float* Cf = (float*)Cout + (long long)bz * sC;
  unsigned short* Cb = (unsigned short*)Cout + (long long)bz * sC;
#pragma unroll
  for (int m = 0; m < 4; ++m) {
    int row0 = bm + (wr << 6) + (m << 4) + (lg << 2);
#pragma unroll
    for (int n = 0; n < 4; ++n) {
      int col = bn + (wc << 6) + (n << 4) + l15;
      if (col >= N) continue;
      float bval = bias ? bias[col] : 0.f;
#pragma unroll
      for (int r = 0; r < 4; ++r) {
        int row = row0 + r;
        float v = acc[m][n][r];
        long long ci = (long long)row * ldc + col;
        if (mode == 0) {
          Cf[ci] = v;
        } else if (mode == 1) {
          Cf[ci] = v + bval;
        } else if (mode == 2) {
          Cf[ci] = v + bval + res[ci];
        } else if (mode == 3) {
          v += bval;
          Cb[ci] = f2bf(v / (1.0f + __expf(-1.702f * v)));
        } else if (mode == 4) {
          v += bval;
          Cb[ci] = f2bf(0.5f * v * (1.0f + tanhf(0.79788456080286535588f *
                                                 (v + 0.044715f * v * v * v))));
        }
      }
    }
  }
}

extern "C" void kernel_launch(void* const* d_in, const int* in_sizes, int n_in,
                              void* d_out, int out_size, void* d_ws, size_t ws_size,
                              hipStream_t stream) {
  const float* x = (const float*)d_in[0];
  const float* patch_w = (const float*)d_in[1];
  const float* ln1_g = (const float*)d_in[2];
  const float* ln1_b = (const float*)d_in[3];
  const float* qkv_w = (const float*)d_in[4];
  const float* qkv_b = (const float*)d_in[5];
  const float* proj_w = (const float*)d_in[6];
  const float* proj_b = (const float*)d_in[7];
  const float* ln2_g = (const float*)d_in[8];
  const float* ln2_b = (const float*)d_in[9];
  const float* fc1_w = (const float*)d_in[10];
  const float* fc1_b = (const float*)d_in[11];
  const float* fc2_w = (const float*)d_in[12];
  const float* fc2_b = (const float*)d_in[13];
  const float* mln_g = (const float*)d_in[14];
  const float* mln_b = (const float*)d_in[15];
  const float* mfc1_w = (const float*)d_in[16];
  const float* mfc1_b = (const float*)d_in[17];
  const float* mfc2_w = (const float*)d_in[18];
  const float* mfc2_b = (const float*)d_in[19];
  const int* grid_h = (const int*)d_in[21];
  const int* grid_w = (const int*)d_in[22];

  char* ws = (char*)d_ws;
  float* h = (float*)ws;                       ws += (size_t)SEQ * EMBED * 4;
  float* qkv = (float*)ws;                     ws += (size_t)SEQ * QKV3 * 4;
  float* cosT = (float*)ws;                    ws += (size_t)SEQ * 40 * 4;
  float* sinT = (float*)ws;                    ws += (size_t)SEQ * 40 * 4;
  unsigned short* y = (unsigned short*)ws;     ws += (size_t)SEQ * EMBED * 2;
  unsigned short* ob = (unsigned short*)ws;    ws += (size_t)SEQ * EMBED * 2;
  unsigned short* m1b = (unsigned short*)ws;   ws += (size_t)MSEQ * MDIM * 2;
  unsigned short* qb = (unsigned short*)ws;    ws += (size_t)HEADS * SEQ * HDP * 2;
  unsigned short* kb = (unsigned short*)ws;    ws += (size_t)HEADS * SEQ * HDP * 2;
  unsigned short* vb = (unsigned short*)ws;    ws += (size_t)HEADS * HD * SEQ * 2;
  unsigned short* wt = (unsigned short*)ws;    ws += (size_t)MDIM * MDIM * 2;
  // union region: u (10.5MB bf16) / xb (2.4MB) — disjoint lifetimes
  unsigned short* u = (unsigned short*)ws;
  unsigned short* xb = (unsigned short*)ws;

  const float scale = 1.0f / sqrtf(80.0f);
  dim3 blk(256);

  rope_tables_kernel<<<SEQ, 64, 0, stream>>>(grid_h, grid_w, cosT, sinT);

  // ---- patch embed: h = x @ patch_w ----
  convert_x<<<(SEQ * PATCH_PAD + 255) / 256, blk, 0, stream>>>(x, xb);
  transpose_w<<<dim3(PATCH_PAD / 32, EMBED / 32), blk, 0, stream>>>(
      patch_w, wt, PATCH_DIMS, PATCH_PAD, EMBED);
  gemm_bt<<<dim3(EMBED / 128, SEQ / 128, 1), blk, 0, stream>>>(
      xb, PATCH_PAD, 0, wt, PATCH_PAD, 0, nullptr, nullptr,
      h, EMBED, 0, SEQ, EMBED, PATCH_PAD, 0, 1.f);

  for (int l = 0; l < DEPTH; ++l) {
    // qkv = LN1(h) @ qkv_w + qkv_b   (f32 out)
    layernorm1280<<<SEQ, 256, 0, stream>>>(h, ln1_g + l * EMBED, ln1_b + l * EMBED, y);
    transpose_w<<<dim3(EMBED / 32, QKV3 / 32), blk, 0, stream>>>(
        qkv_w + (long long)l * EMBED * QKV3, wt, EMBED, EMBED, QKV3);
    gemm_bt<<<dim3(QKV3 / 128, SEQ / 128, 1), blk, 0, stream>>>(
        y, EMBED, 0, wt, EMBED, 0, qkv_b + l * QKV3, nullptr,
        qkv, QKV3, 0, SEQ, QKV3, EMBED, 1, 1.f);
    // fused rope+scale+pad pack of q,k; LDS-transposed pack of v
    pack_qk_rope<<<(SEQ * HEADS * 48) / 256, blk, 0, stream>>>(
        qkv, cosT, sinT, qb, kb, scale);
    pack_v<<<dim3(16, HEADS), blk, 0, stream>>>(qkv, vb);
    // fused attention -> ob
    flash_attn<<<dim3(SEQ / 64, HEADS), blk, 0, stream>>>(qb, kb, vb, ob);
    // h += o @ proj_w + proj_b
    transpose_w<<<dim3(EMBED / 32, EMBED / 32), blk, 0, stream>>>(
        proj_w + (long long)l * EMBED * EMBED, wt, EMBED, EMBED, EMBED);
    gemm_bt<<<dim3(EMBED / 128, SEQ / 128, 1), blk, 0, stream>>>(
        ob, EMBED, 0, wt, EMBED, 0, proj_b + l * EMBED, h,
        h, EMBED, 0, SEQ, EMBED, EMBED, 2, 1.f);
    // u = swish(LN2(h) @ fc1_w + fc1_b)  (bf16 out)
    layernorm1280<<<SEQ, 256, 0, stream>>>(h, ln2_g + l * EMBED, ln2_b + l * EMBED, y);
    transpose_w<<<dim3(EMBED / 32, MLP_DIM / 32), blk, 0, stream>>>(
        fc1_w + (long long)l * EMBED * MLP_DIM, wt, EMBED, EMBED, MLP_DIM);
    gemm_bt<<<dim3(MLP_DIM / 128, SEQ / 128, 1), blk, 0, stream>>>(
        y, EMBED, 0, wt, EMBED, 0, fc1_b + l * MLP_DIM, nullptr,
        u, MLP_DIM, 0, SEQ, MLP_DIM, EMBED, 3, 1.f);
    // h += u @ fc2_w + fc2_b
    transpose_w<<<dim3(MLP_DIM / 32, EMBED / 32), blk, 0, stream>>>(
        fc2_w + (long long)l * MLP_DIM * EMBED, wt, MLP_DIM, MLP_DIM, EMBED);
    gemm_bt<<<dim3(EMBED / 128, SEQ / 128, 1), blk, 0, stream>>>(
        u, MLP_DIM, 0, wt, MLP_DIM, 0, fc2_b + l * EMBED, h,
        h, EMBED, 0, SEQ, EMBED, MLP_DIM, 2, 1.f);
  }

  // ---- merger ----
  layernorm1280<<<SEQ, 256, 0, stream>>>(h, mln_g, mln_b, y);
  transpose_w<<<dim3(MDIM / 32, MDIM / 32), blk, 0, stream>>>(
      mfc1_w, wt, MDIM, MDIM, MDIM);
  gemm_bt<<<dim3(MDIM / 128, MSEQ / 128, 1), blk, 0, stream>>>(
      y, MDIM, 0, wt, MDIM, 0, mfc1_b, nullptr,
      m1b, MDIM, 0, MSEQ, MDIM, MDIM, 4, 1.f);
  transpose_w<<<dim3(MDIM / 32, HIDDEN / 32), blk, 0, stream>>>(
      mfc2_w, wt, MDIM, MDIM, HIDDEN);
  gemm_bt<<<dim3(HIDDEN / 128, MSEQ / 128, 1), blk, 0, stream>>>(
      m1b, MDIM, 0, wt, MDIM, 0, mfc2_b, nullptr,
      (float*)d_out, HIDDEN, 0, MSEQ, HIDDEN, MDIM, 1, 1.f);
}

// Round 4
// 2104.960 us; speedup vs baseline: 8.5740x; 1.6348x over previous
//
#include <hip/hip_runtime.h>
#include <hip/hip_bf16.h>
#include <cmath>

#define SEQ 1024
#define EMBED 1280
#define HEADS 16
#define HD 80
#define HDP 96
#define MLP_DIM 5120
#define HIDDEN 3584
#define QKV3 3840
#define PATCH_DIMS 1176
#define PATCH_PAD 1184
#define DEPTH 8
#define MSEQ 256
#define MDIM 5120

typedef short short8 __attribute__((ext_vector_type(8)));
typedef short short4v __attribute__((ext_vector_type(4)));
typedef float f32x4 __attribute__((ext_vector_type(4)));

#define GLOAD16(g, l)                                                          \
  __builtin_amdgcn_global_load_lds(                                            \
      (const __attribute__((address_space(1))) void*)(g),                      \
      (__attribute__((address_space(3))) void*)(l), 16, 0, 0)

__device__ __forceinline__ float bf2f(unsigned short u) {
  union { unsigned int i; float f; } x;
  x.i = ((unsigned int)u) << 16;
  return x.f;
}
__device__ __forceinline__ unsigned short f2bf(float f) {
  union { float f; unsigned int i; } x;
  x.f = f;
  unsigned int r = x.i + 0x7fffu + ((x.i >> 16) & 1u);
  return (unsigned short)(r >> 16);
}

// ---------------- reductions ----------------
__device__ inline float waveReduceSum(float v) {
#pragma unroll
  for (int o = 32; o; o >>= 1) v += __shfl_xor(v, o);
  return v;
}

// ---------------- RoPE tables ----------------
__global__ void rope_tables_kernel(const int* gh_p, const int* gw_p,
                                   float* __restrict__ cosT, float* __restrict__ sinT) {
  int s = blockIdx.x;
  int j = threadIdx.x;
  if (j >= 40) return;
  int gh = *gh_p, gw = *gw_p;
  int f = s % (gh * gw);
  int d0 = f & 1;
  int b = (f >> 1) & 1;
  int rest = f >> 2;
  int W2 = gw >> 1;
  int c = rest % W2;
  int a = rest / W2;
  int hpos = a * 2 + b;
  int wpos = c * 2 + d0;
  int jp = j % 20;
  float inv = powf(10000.0f, -(2.0f * (float)jp) / 40.0f);
  float val = (float)(j < 20 ? hpos : wpos) * inv;
  cosT[s * 40 + j] = cosf(val);
  sinT[s * 40 + j] = sinf(val);
}

// ---------------- LayerNorm 1280 : f32 in -> bf16 out ----------------
__global__ __launch_bounds__(256) void layernorm1280(const float* __restrict__ x,
                                                     const float* __restrict__ g,
                                                     const float* __restrict__ b,
                                                     unsigned short* __restrict__ y) {
  const float* row = x + (size_t)blockIdx.x * EMBED;
  unsigned short* out = y + (size_t)blockIdx.x * EMBED;
  int tid = threadIdx.x;
  __shared__ float r0[4], r1[4];
  float v[5];
  float s = 0.f, sq = 0.f;
#pragma unroll
  for (int i = 0; i < 5; ++i) {
    v[i] = row[tid + (i << 8)];
    s += v[i];
    sq += v[i] * v[i];
  }
  float ws1 = waveReduceSum(s);
  float ws2 = waveReduceSum(sq);
  int lane = tid & 63, wid = tid >> 6;
  if (!lane) { r0[wid] = ws1; r1[wid] = ws2; }
  __syncthreads();
  s = r0[0] + r0[1] + r0[2] + r0[3];
  sq = r1[0] + r1[1] + r1[2] + r1[3];
  float mean = s * (1.0f / EMBED);
  float var = sq * (1.0f / EMBED) - mean * mean;
  float rstd = rsqrtf(var + 1e-6f);
#pragma unroll
  for (int i = 0; i < 5; ++i) {
    int col = tid + (i << 8);
    out[col] = f2bf((v[i] - mean) * rstd * g[col] + b[col]);
  }
}

// ---------------- weight transpose+convert: f32 [Ksrc][ldW] -> bf16 [N][Kpad] ----------------
__global__ __launch_bounds__(256) void transpose_w(const float* __restrict__ W, int ldW,
                                                   unsigned short* __restrict__ Wt,
                                                   int Ksrc, int Kpad) {
  __shared__ float t[32][33];
  int k0 = blockIdx.x * 32, n0 = blockIdx.y * 32;
  int tx = threadIdx.x & 31, ty = threadIdx.x >> 5;  // 32 x 8
#pragma unroll
  for (int i = 0; i < 32; i += 8) {
    int k = k0 + ty + i;
    t[ty + i][tx] = (k < Ksrc) ? W[(long long)k * ldW + n0 + tx] : 0.f;
  }
  __syncthreads();
#pragma unroll
  for (int i = 0; i < 32; i += 8) {
    Wt[(long long)(n0 + ty + i) * Kpad + k0 + tx] = f2bf(t[tx][ty + i]);
  }
}

// ---------------- x convert: f32 [1024][1176] -> bf16 [1024][1184] ----------------
__global__ __launch_bounds__(256) void convert_x(const float* __restrict__ x,
                                                 unsigned short* __restrict__ xb) {
  int idx = blockIdx.x * 256 + threadIdx.x;
  if (idx >= SEQ * PATCH_PAD) return;
  int j = idx % PATCH_PAD, s = idx / PATCH_PAD;
  xb[idx] = (j < PATCH_DIMS) ? f2bf(x[(long long)s * PATCH_DIMS + j]) : 0;
}

// ---------------- fused RoPE + pack q,k: f32 qkv -> bf16 qb,kb [h][s][96] ----------------
__global__ __launch_bounds__(256) void pack_qk_rope(
    const float* __restrict__ qkv,
    const float* __restrict__ cosT, const float* __restrict__ sinT,
    unsigned short* __restrict__ qb, unsigned short* __restrict__ kb,
    float qscale) {
  int idx = blockIdx.x * 256 + threadIdx.x;  // SEQ*HEADS*48
  int d = idx % 48;
  int hh = (idx / 48) % HEADS;
  int s = idx / (48 * HEADS);
  if (s >= SEQ) return;
  size_t ob = ((size_t)hh * SEQ + s) * HDP;
  if (d >= 40) {
    int p = 80 + (d - 40) * 2;
    qb[ob + p] = 0; qb[ob + p + 1] = 0;
    kb[ob + p] = 0; kb[ob + p + 1] = 0;
    return;
  }
  float cs = cosT[s * 40 + d], sn = sinT[s * 40 + d];
  size_t src = (size_t)s * QKV3 + hh * HD + d;
  float q0 = qkv[src], q1 = qkv[src + 40];
  float k0 = qkv[src + EMBED], k1 = qkv[src + EMBED + 40];
  qb[ob + d] = f2bf((q0 * cs - q1 * sn) * qscale);
  qb[ob + d + 40] = f2bf((q1 * cs + q0 * sn) * qscale);
  kb[ob + d] = f2bf(k0 * cs - k1 * sn);
  kb[ob + d + 40] = f2bf(k1 * cs + k0 * sn);
}

// ---------------- pack V transposed: f32 qkv -> bf16 vb [h][80][1024] ----------------
__global__ __launch_bounds__(256) void pack_v(const float* __restrict__ qkv,
                                              unsigned short* __restrict__ vb) {
  __shared__ unsigned short t[80][72];
  int hh = blockIdx.y, s0 = blockIdx.x << 6;
  int tid = threadIdx.x;
  int s = tid >> 2, c0 = (tid & 3) * 20;
  const float* src = qkv + (size_t)(s0 + s) * QKV3 + 2 * EMBED + hh * HD + c0;
#pragma unroll
  for (int j = 0; j < 20; ++j) t[c0 + j][s] = f2bf(src[j]);
  __syncthreads();
  unsigned short* dst = vb + (size_t)hh * 80 * SEQ + s0;
#pragma unroll
  for (int i = 0; i < 3; ++i) {
    int c = tid + (i << 8);
    if (c < 640) {
      int dr = c >> 3, col = (c & 7) << 3;
      *(short8*)&dst[(size_t)dr * SEQ + col] = *(const short8*)&t[dr][col];
    }
  }
}

// ---------------- fused flash attention ----------------
__global__ __launch_bounds__(256) void flash_attn(
    const unsigned short* __restrict__ qb,
    const unsigned short* __restrict__ kb,
    const unsigned short* __restrict__ vb,
    unsigned short* __restrict__ ob) {
  __shared__ short Ks[64 * 104];
  __shared__ short Vs[80 * 72];
  __shared__ short Ps[4 * 16 * 72];
  int h = blockIdx.y, q0 = blockIdx.x << 6;
  int tid = threadIdx.x, lane = tid & 63, wid = tid >> 6;
  int l15 = lane & 15, lg = lane >> 4;
  int kb8 = lg << 3;

  short8 qf[3];
  {
    const unsigned short* qrow = qb + ((size_t)h * SEQ + q0 + (wid << 4) + l15) * HDP;
#pragma unroll
    for (int dc = 0; dc < 3; ++dc) qf[dc] = *(const short8*)&qrow[dc * 32 + kb8];
  }

  f32x4 o_acc[5] = {};
  float m_run = -1e30f, l_run = 0.f;
  short* myP = &Ps[(wid * 16 + l15) * 72];

  for (int t = 0; t < 16; ++t) {
    int kv0 = t << 6;
    __syncthreads();
    {
      const unsigned short* gk = kb + ((size_t)h * SEQ + kv0) * HDP;
#pragma unroll
      for (int i = 0; i < 3; ++i) {
        int c = tid + (i << 8);
        int row = c / 12, col = (c % 12) << 3;
        *(short8*)&Ks[row * 104 + col] = *(const short8*)&gk[row * HDP + col];
      }
      const unsigned short* gv = vb + (size_t)h * 80 * SEQ + kv0;
#pragma unroll
      for (int i = 0; i < 3; ++i) {
        int c = tid + (i << 8);
        if (c < 640) {
          int row = c >> 3, col = (c & 7) << 3;
          *(short8*)&Vs[row * 72 + col] = *(const short8*)&gv[(size_t)row * SEQ + col];
        }
      }
    }
    __syncthreads();

    f32x4 s[4] = {};
#pragma unroll
    for (int ks = 0; ks < 4; ++ks) {
#pragma unroll
      for (int dc = 0; dc < 3; ++dc) {
        short8 kf = *(const short8*)&Ks[(ks * 16 + l15) * 104 + dc * 32 + kb8];
        s[ks] = __builtin_amdgcn_mfma_f32_16x16x32_bf16(kf, qf[dc], s[ks], 0, 0, 0);
      }
    }

    float mloc = -1e30f;
#pragma unroll
    for (int ks = 0; ks < 4; ++ks)
#pragma unroll
      for (int r = 0; r < 4; ++r) mloc = fmaxf(mloc, s[ks][r]);
    mloc = fmaxf(mloc, __shfl_xor(mloc, 16));
    mloc = fmaxf(mloc, __shfl_xor(mloc, 32));
    float m_new = fmaxf(m_run, mloc);
    float alpha = __expf(m_run - m_new);
    float psum = 0.f;
#pragma unroll
    for (int ks = 0; ks < 4; ++ks) {
      short4v pk;
#pragma unroll
      for (int r = 0; r < 4; ++r) {
        float p = __expf(s[ks][r] - m_new);
        psum += p;
        pk[r] = (short)f2bf(p);
      }
      *(short4v*)&myP[ks * 16 + (lg << 2)] = pk;
    }
    psum += __shfl_xor(psum, 16);
    psum += __shfl_xor(psum, 32);
    l_run = l_run * alpha + psum;
    m_run = m_new;
#pragma unroll
    for (int dt = 0; dt < 5; ++dt)
#pragma unroll
      for (int r = 0; r < 4; ++r) o_acc[dt][r] *= alpha;

#pragma unroll
    for (int dt = 0; dt < 5; ++dt) {
#pragma unroll
      for (int kc = 0; kc < 2; ++kc) {
        short8 vf = *(const short8*)&Vs[(dt * 16 + l15) * 72 + kc * 32 + kb8];
        short8 pf = *(const short8*)&myP[kc * 32 + kb8];
        o_acc[dt] = __builtin_amdgcn_mfma_f32_16x16x32_bf16(vf, pf, o_acc[dt], 0, 0, 0);
      }
    }
  }

  float inv = 1.0f / l_run;
  unsigned short* orow = ob + (size_t)(q0 + (wid << 4) + l15) * EMBED + h * HD;
#pragma unroll
  for (int dt = 0; dt < 5; ++dt) {
    short4v ov;
#pragma unroll
    for (int r = 0; r < 4; ++r) ov[r] = (short)f2bf(o_acc[dt][r] * inv);
    *(short4v*)&orow[dt * 16 + (lg << 2)] = ov;
  }
}

// ---------------- split-K bf16 MFMA GEMM: Cpart[z] = A(M x Kchunk) * Bt^T ----------------
__global__ __launch_bounds__(256) void gemm_sk(
    const unsigned short* __restrict__ A, int lda,
    const unsigned short* __restrict__ Bt, int ldb,
    float* __restrict__ Cpart,
    int M, int N, int K, int chunk) {
  __shared__ short As[128 * 32];
  __shared__ short Bs[128 * 32];
  int bm = blockIdx.y << 7, bn = blockIdx.x << 7;
  int k0 = blockIdx.z * chunk;
  int kend = min(K, k0 + chunk);
  int tid = threadIdx.x;
  int lane = tid & 63, wid = tid >> 6;
  int wr = wid >> 1, wc = wid & 1;
  f32x4 acc[4][4] = {};

  int arow = (wid << 4) + (lane >> 2);
  int kblk = (lane & 3) << 3;
  const unsigned short* ga = A + (long long)(bm + arow) * lda + k0 + kblk;
  const unsigned short* gb = Bt + (long long)(bn + arow) * ldb + k0 + kblk;
  short* la = &As[arow * 32 + kblk];
  short* lb = &Bs[arow * 32 + kblk];
  long long stepA = 64LL * lda, stepB = 64LL * ldb;

  int l15 = lane & 15, kb8 = (lane >> 4) << 3;
  int rowA = (wr << 6) + l15;
  int rowB = (wc << 6) + l15;

  for (int k = k0; k < kend; k += 32) {
    __syncthreads();
    GLOAD16(ga, la);
    GLOAD16(ga + stepA, la + 64 * 32);
    GLOAD16(gb, lb);
    GLOAD16(gb + stepB, lb + 64 * 32);
    ga += 32;
    gb += 32;
    __syncthreads();
    short8 af[4], bfr[4];
#pragma unroll
    for (int m = 0; m < 4; ++m)
      af[m] = *(const short8*)&As[(rowA + (m << 4)) * 32 + kb8];
#pragma unroll
    for (int n = 0; n < 4; ++n)
      bfr[n] = *(const short8*)&Bs[(rowB + (n << 4)) * 32 + kb8];
#pragma unroll
    for (int m = 0; m < 4; ++m)
#pragma unroll
      for (int n = 0; n < 4; ++n)
        acc[m][n] = __builtin_amdgcn_mfma_f32_16x16x32_bf16(af[m], bfr[n], acc[m][n], 0, 0, 0);
  }

  int lg = lane >> 4;
  float* Cp = Cpart + (long long)blockIdx.z * M * N;
#pragma unroll
  for (int m = 0; m < 4; ++m) {
    int row0 = bm + (wr << 6) + (m << 4) + (lg << 2);
#pragma unroll
    for (int n = 0; n < 4; ++n) {
      int col = bn + (wc << 6) + (n << 4) + l15;
#pragma unroll
      for (int r = 0; r < 4; ++r) {
        Cp[(long long)(row0 + r) * N + col] = acc[m][n][r];
      }
    }
  }
}

// ---------------- split-K reduce + epilogue ----------------
// mode: 0 f32 (+bias if non-null) | 2 f32 +bias +res | 3 bf16 swish+bias | 4 bf16 gelu+bias
__global__ __launch_bounds__(256) void reduce_sk(
    const float* __restrict__ P, long long MN, int nsplit,
    const float* __restrict__ bias, const float* __restrict__ res,
    void* __restrict__ out, int N, int ldout, int colbase, int mode) {
  long long i = ((long long)blockIdx.x * 256 + threadIdx.x) * 4;
  if (i >= MN) return;
  float4 acc = *(const float4*)&P[i];
  for (int s = 1; s < nsplit; ++s) {
    float4 p = *(const float4*)&P[s * MN + i];
    acc.x += p.x; acc.y += p.y; acc.z += p.z; acc.w += p.w;
  }
  int row = (int)(i / N), col = (int)(i % N);
  float v[4] = {acc.x, acc.y, acc.z, acc.w};
  if (bias) {
    float4 bv = *(const float4*)&bias[col];
    v[0] += bv.x; v[1] += bv.y; v[2] += bv.z; v[3] += bv.w;
  }
  long long oi = (long long)row * ldout + colbase + col;
  if (mode == 0) {
    *(float4*)&((float*)out)[oi] = make_float4(v[0], v[1], v[2], v[3]);
  } else if (mode == 2) {
    float4 rv = *(const float4*)&((const float*)res)[oi];
    *(float4*)&((float*)out)[oi] =
        make_float4(v[0] + rv.x, v[1] + rv.y, v[2] + rv.z, v[3] + rv.w);
  } else if (mode == 3) {
    short4v o;
#pragma unroll
    for (int j = 0; j < 4; ++j)
      o[j] = (short)f2bf(v[j] / (1.0f + __expf(-1.702f * v[j])));
    *(short4v*)&((unsigned short*)out)[oi] = o;
  } else {
    short4v o;
#pragma unroll
    for (int j = 0; j < 4; ++j)
      o[j] = (short)f2bf(0.5f * v[j] * (1.0f + tanhf(0.79788456080286535588f *
                                                     (v[j] + 0.044715f * v[j] * v[j] * v[j]))));
    *(short4v*)&((unsigned short*)out)[oi] = o;
  }
}

extern "C" void kernel_launch(void* const* d_in, const int* in_sizes, int n_in,
                              void* d_out, int out_size, void* d_ws, size_t ws_size,
                              hipStream_t stream) {
  const float* x = (const float*)d_in[0];
  const float* patch_w = (const float*)d_in[1];
  const float* ln1_g = (const float*)d_in[2];
  const float* ln1_b = (const float*)d_in[3];
  const float* qkv_w = (const float*)d_in[4];
  const float* qkv_b = (const float*)d_in[5];
  const float* proj_w = (const float*)d_in[6];
  const float* proj_b = (const float*)d_in[7];
  const float* ln2_g = (const float*)d_in[8];
  const float* ln2_b = (const float*)d_in[9];
  const float* fc1_w = (const float*)d_in[10];
  const float* fc1_b = (const float*)d_in[11];
  const float* fc2_w = (const float*)d_in[12];
  const float* fc2_b = (const float*)d_in[13];
  const float* mln_g = (const float*)d_in[14];
  const float* mln_b = (const float*)d_in[15];
  const float* mfc1_w = (const float*)d_in[16];
  const float* mfc1_b = (const float*)d_in[17];
  const float* mfc2_w = (const float*)d_in[18];
  const float* mfc2_b = (const float*)d_in[19];
  const int* grid_h = (const int*)d_in[21];
  const int* grid_w = (const int*)d_in[22];

  char* wsp = (char*)d_ws;
  char* ws0 = wsp;
  float* h = (float*)wsp;                       wsp += (size_t)SEQ * EMBED * 4;
  float* qkv = (float*)wsp;                     wsp += (size_t)SEQ * QKV3 * 4;
  float* cosT = (float*)wsp;                    wsp += (size_t)SEQ * 40 * 4;
  float* sinT = (float*)wsp;                    wsp += (size_t)SEQ * 40 * 4;
  unsigned short* y = (unsigned short*)wsp;     wsp += (size_t)SEQ * EMBED * 2;
  unsigned short* ob = (unsigned short*)wsp;    wsp += (size_t)SEQ * EMBED * 2;
  unsigned short* m1b = (unsigned short*)wsp;   wsp += (size_t)MSEQ * MDIM * 2;
  unsigned short* qb = (unsigned short*)wsp;    wsp += (size_t)HEADS * SEQ * HDP * 2;
  unsigned short* kb = (unsigned short*)wsp;    wsp += (size_t)HEADS * SEQ * HDP * 2;
  unsigned short* vb = (unsigned short*)wsp;    wsp += (size_t)HEADS * HD * SEQ * 2;
  unsigned short* u = (unsigned short*)wsp;     wsp += (size_t)SEQ * MLP_DIM * 2;
  unsigned short* xb = (unsigned short*)wsp;    wsp += (size_t)SEQ * PATCH_PAD * 2;
  unsigned short* wt = (unsigned short*)wsp;    wsp += (size_t)(MDIM / 2) * MDIM * 2;
  float* part = (float*)wsp;
  size_t fixed = (size_t)(wsp - ws0);
  size_t avail = ws_size > fixed ? ws_size - fixed : 0;

  auto splits_for = [&](long long MN, int want) {
    size_t one = (size_t)MN * 4;
    if (avail < one) return 1;
    long long cap = (long long)(avail / one);
    return (int)(want < cap ? want : cap);
  };
  auto chunk_for = [](int K, int s) { return ((K + s * 32 - 1) / (s * 32)) * 32; };

  const float scale = 1.0f / sqrtf(80.0f);
  dim3 blk(256);

  rope_tables_kernel<<<SEQ, 64, 0, stream>>>(grid_h, grid_w, cosT, sinT);

  // ---- patch embed: h = x @ patch_w ----
  convert_x<<<(SEQ * PATCH_PAD + 255) / 256, blk, 0, stream>>>(x, xb);
  transpose_w<<<dim3(PATCH_PAD / 32, EMBED / 32), blk, 0, stream>>>(
      patch_w, EMBED, wt, PATCH_DIMS, PATCH_PAD);
  {
    long long MN = (long long)SEQ * EMBED;
    int s = splits_for(MN, 4), ch = chunk_for(PATCH_PAD, s);
    gemm_sk<<<dim3(EMBED / 128, SEQ / 128, s), blk, 0, stream>>>(
        xb, PATCH_PAD, wt, PATCH_PAD, part, SEQ, EMBED, PATCH_PAD, ch);
    reduce_sk<<<(MN / 4 + 255) / 256, blk, 0, stream>>>(
        part, MN, s, nullptr, nullptr, h, EMBED, EMBED, 0, 0);
  }

  for (int l = 0; l < DEPTH; ++l) {
    // qkv = LN1(h) @ qkv_w + qkv_b   (f32 out)
    layernorm1280<<<SEQ, 256, 0, stream>>>(h, ln1_g + l * EMBED, ln1_b + l * EMBED, y);
    transpose_w<<<dim3(EMBED / 32, QKV3 / 32), blk, 0, stream>>>(
        qkv_w + (long long)l * EMBED * QKV3, QKV3, wt, EMBED, EMBED);
    {
      long long MN = (long long)SEQ * QKV3;
      int s = splits_for(MN, 2), ch = chunk_for(EMBED, s);
      gemm_sk<<<dim3(QKV3 / 128, SEQ / 128, s), blk, 0, stream>>>(
          y, EMBED, wt, EMBED, part, SEQ, QKV3, EMBED, ch);
      reduce_sk<<<(MN / 4 + 255) / 256, blk, 0, stream>>>(
          part, MN, s, qkv_b + l * QKV3, nullptr, qkv, QKV3, QKV3, 0, 0);
    }
    pack_qk_rope<<<(SEQ * HEADS * 48) / 256, blk, 0, stream>>>(
        qkv, cosT, sinT, qb, kb, scale);
    pack_v<<<dim3(16, HEADS), blk, 0, stream>>>(qkv, vb);
    flash_attn<<<dim3(SEQ / 64, HEADS), blk, 0, stream>>>(qb, kb, vb, ob);
    // h += o @ proj_w + proj_b
    transpose_w<<<dim3(EMBED / 32, EMBED / 32), blk, 0, stream>>>(
        proj_w + (long long)l * EMBED * EMBED, EMBED, wt, EMBED, EMBED);
    {
      long long MN = (long long)SEQ * EMBED;
      int s = splits_for(MN, 4), ch = chunk_for(EMBED, s);
      gemm_sk<<<dim3(EMBED / 128, SEQ / 128, s), blk, 0, stream>>>(
          ob, EMBED, wt, EMBED, part, SEQ, EMBED, EMBED, ch);
      reduce_sk<<<(MN / 4 + 255) / 256, blk, 0, stream>>>(
          part, MN, s, proj_b + l * EMBED, h, h, EMBED, EMBED, 0, 2);
    }
    // u = swish(LN2(h) @ fc1_w + fc1_b)  (bf16 out)
    layernorm1280<<<SEQ, 256, 0, stream>>>(h, ln2_g + l * EMBED, ln2_b + l * EMBED, y);
    transpose_w<<<dim3(EMBED / 32, MLP_DIM / 32), blk, 0, stream>>>(
        fc1_w + (long long)l * EMBED * MLP_DIM, MLP_DIM, wt, EMBED, EMBED);
    {
      long long MN = (long long)SEQ * MLP_DIM;
      int s = splits_for(MN, 2), ch = chunk_for(EMBED, s);
      gemm_sk<<<dim3(MLP_DIM / 128, SEQ / 128, s), blk, 0, stream>>>(
          y, EMBED, wt, EMBED, part, SEQ, MLP_DIM, EMBED, ch);
      reduce_sk<<<(MN / 4 + 255) / 256, blk, 0, stream>>>(
          part, MN, s, fc1_b + l * MLP_DIM, nullptr, u, MLP_DIM, MLP_DIM, 0, 3);
    }
    // h += u @ fc2_w + fc2_b
    transpose_w<<<dim3(MLP_DIM / 32, EMBED / 32), blk, 0, stream>>>(
        fc2_w + (long long)l * MLP_DIM * EMBED, EMBED, wt, MLP_DIM, MLP_DIM);
    {
      long long MN = (long long)SEQ * EMBED;
      int s = splits_for(MN, 8), ch = chunk_for(MLP_DIM, s);
      gemm_sk<<<dim3(EMBED / 128, SEQ / 128, s), blk, 0, stream>>>(
          u, MLP_DIM, wt, MLP_DIM, part, SEQ, EMBED, MLP_DIM, ch);
      reduce_sk<<<(MN / 4 + 255) / 256, blk, 0, stream>>>(
          part, MN, s, fc2_b + l * EMBED, h, h, EMBED, EMBED, 0, 2);
    }
  }

  // ---- merger ----
  layernorm1280<<<SEQ, 256, 0, stream>>>(h, mln_g, mln_b, y);
  // mfc1 in two N-halves of 2560
  for (int hh = 0; hh < 2; ++hh) {
    transpose_w<<<dim3(MDIM / 32, 2560 / 32), blk, 0, stream>>>(
        mfc1_w + hh * 2560, MDIM, wt, MDIM, MDIM);
    long long MN = (long long)MSEQ * 2560;
    int s = splits_for(MN, 8), ch = chunk_for(MDIM, s);
    gemm_sk<<<dim3(2560 / 128, MSEQ / 128, s), blk, 0, stream>>>(
        y, MDIM, wt, MDIM, part, MSEQ, 2560, MDIM, ch);
    reduce_sk<<<(MN / 4 + 255) / 256, blk, 0, stream>>>(
        part, MN, s, mfc1_b + hh * 2560, nullptr, m1b, 2560, MDIM, hh * 2560, 4);
  }
  // mfc2 in two N-halves of 1792
  for (int hh = 0; hh < 2; ++hh) {
    transpose_w<<<dim3(MDIM / 32, 1792 / 32), blk, 0, stream>>>(
        mfc2_w + hh * 1792, HIDDEN, wt, MDIM, MDIM);
    long long MN = (long long)MSEQ * 1792;
    int s = splits_for(MN, 8), ch = chunk_for(MDIM, s);
    gemm_sk<<<dim3(1792 / 128, MSEQ / 128, s), blk, 0, stream>>>(
        m1b, MDIM, wt, MDIM, part, MSEQ, 1792, MDIM, ch);
    reduce_sk<<<(MN / 4 + 255) / 256, blk, 0, stream>>>(
        part, MN, s, mfc2_b + hh * 1792, nullptr, (float*)d_out, 1792, HIDDEN, hh * 1792, 0);
  }
}

// Round 5
// 2089.558 us; speedup vs baseline: 8.6372x; 1.0074x over previous
//
#include <hip/hip_runtime.h>
#include <hip/hip_bf16.h>
#include <cmath>

#define SEQ 1024
#define EMBED 1280
#define HEADS 16
#define HD 80
#define HDP 96
#define MLP_DIM 5120
#define HIDDEN 3584
#define QKV3 3840
#define PATCH_DIMS 1176
#define PATCH_PAD 1184
#define DEPTH 8
#define MSEQ 256
#define MDIM 5120

typedef short short8 __attribute__((ext_vector_type(8)));
typedef short short4v __attribute__((ext_vector_type(4)));
typedef float f32x4 __attribute__((ext_vector_type(4)));

#define GLOAD16(g, l)                                                          \
  __builtin_amdgcn_global_load_lds(                                            \
      (const __attribute__((address_space(1))) void*)(g),                      \
      (__attribute__((address_space(3))) void*)(l), 16, 0, 0)

__device__ __forceinline__ float bf2f(unsigned short u) {
  union { unsigned int i; float f; } x;
  x.i = ((unsigned int)u) << 16;
  return x.f;
}
__device__ __forceinline__ unsigned short f2bf(float f) {
  union { float f; unsigned int i; } x;
  x.f = f;
  unsigned int r = x.i + 0x7fffu + ((x.i >> 16) & 1u);
  return (unsigned short)(r >> 16);
}

__device__ inline float waveReduceSum(float v) {
#pragma unroll
  for (int o = 32; o; o >>= 1) v += __shfl_xor(v, o);
  return v;
}

// ---------------- RoPE tables ----------------
__global__ void rope_tables_kernel(const int* gh_p, const int* gw_p,
                                   float* __restrict__ cosT, float* __restrict__ sinT) {
  int s = blockIdx.x;
  int j = threadIdx.x;
  if (j >= 40) return;
  int gh = *gh_p, gw = *gw_p;
  int f = s % (gh * gw);
  int d0 = f & 1;
  int b = (f >> 1) & 1;
  int rest = f >> 2;
  int W2 = gw >> 1;
  int c = rest % W2;
  int a = rest / W2;
  int hpos = a * 2 + b;
  int wpos = c * 2 + d0;
  int jp = j % 20;
  float inv = powf(10000.0f, -(2.0f * (float)jp) / 40.0f);
  float val = (float)(j < 20 ? hpos : wpos) * inv;
  cosT[s * 40 + j] = cosf(val);
  sinT[s * 40 + j] = sinf(val);
}

// ---------------- weight transpose+convert (z-batched over layers) ----------------
// f32 [Ksrc][ldW] (+ z*wstep) -> bf16 [N][Kpad] (+ z*tstep)
__global__ __launch_bounds__(256) void transpose_w(
    const float* __restrict__ W, int ldW, long long wstep,
    unsigned short* __restrict__ Wt, long long tstep, int Ksrc, int Kpad) {
  __shared__ float t[32][33];
  W += (long long)blockIdx.z * wstep;
  Wt += (long long)blockIdx.z * tstep;
  int k0 = blockIdx.x * 32, n0 = blockIdx.y * 32;
  int tx = threadIdx.x & 31, ty = threadIdx.x >> 5;  // 32 x 8
#pragma unroll
  for (int i = 0; i < 32; i += 8) {
    int k = k0 + ty + i;
    t[ty + i][tx] = (k < Ksrc) ? W[(long long)k * ldW + n0 + tx] : 0.f;
  }
  __syncthreads();
#pragma unroll
  for (int i = 0; i < 32; i += 8) {
    Wt[(long long)(n0 + ty + i) * Kpad + k0 + tx] = f2bf(t[tx][ty + i]);
  }
}

// ---------------- x convert: f32 [1024][1176] -> bf16 [1024][1184] ----------------
__global__ __launch_bounds__(256) void convert_x(const float* __restrict__ x,
                                                 unsigned short* __restrict__ xb) {
  int idx = blockIdx.x * 256 + threadIdx.x;
  if (idx >= SEQ * PATCH_PAD) return;
  int j = idx % PATCH_PAD, s = idx / PATCH_PAD;
  xb[idx] = (j < PATCH_DIMS) ? f2bf(x[(long long)s * PATCH_DIMS + j]) : 0;
}

// ---------------- split-K bf16 MFMA GEMM: Cpart[z] = A(M x Kchunk) * Bt^T ----------------
__global__ __launch_bounds__(256) void gemm_sk(
    const unsigned short* __restrict__ A, int lda,
    const unsigned short* __restrict__ Bt, int ldb,
    float* __restrict__ Cpart,
    int M, int N, int K, int chunk) {
  __shared__ short As[128 * 32];
  __shared__ short Bs[128 * 32];
  int bm = blockIdx.y << 7, bn = blockIdx.x << 7;
  int k0 = blockIdx.z * chunk;
  int kend = min(K, k0 + chunk);
  int tid = threadIdx.x;
  int lane = tid & 63, wid = tid >> 6;
  int wr = wid >> 1, wc = wid & 1;
  f32x4 acc[4][4] = {};

  int arow = (wid << 4) + (lane >> 2);
  int kblk = (lane & 3) << 3;
  const unsigned short* ga = A + (long long)(bm + arow) * lda + k0 + kblk;
  const unsigned short* gb = Bt + (long long)(bn + arow) * ldb + k0 + kblk;
  short* la = &As[arow * 32 + kblk];
  short* lb = &Bs[arow * 32 + kblk];
  long long stepA = 64LL * lda, stepB = 64LL * ldb;

  int l15 = lane & 15, kb8 = (lane >> 4) << 3;
  int rowA = (wr << 6) + l15;
  int rowB = (wc << 6) + l15;

  for (int k = k0; k < kend; k += 32) {
    __syncthreads();
    GLOAD16(ga, la);
    GLOAD16(ga + stepA, la + 64 * 32);
    GLOAD16(gb, lb);
    GLOAD16(gb + stepB, lb + 64 * 32);
    ga += 32;
    gb += 32;
    __syncthreads();
    short8 af[4], bfr[4];
#pragma unroll
    for (int m = 0; m < 4; ++m)
      af[m] = *(const short8*)&As[(rowA + (m << 4)) * 32 + kb8];
#pragma unroll
    for (int n = 0; n < 4; ++n)
      bfr[n] = *(const short8*)&Bs[(rowB + (n << 4)) * 32 + kb8];
#pragma unroll
    for (int m = 0; m < 4; ++m)
#pragma unroll
      for (int n = 0; n < 4; ++n)
        acc[m][n] = __builtin_amdgcn_mfma_f32_16x16x32_bf16(af[m], bfr[n], acc[m][n], 0, 0, 0);
  }

  int lg = lane >> 4;
  float* Cp = Cpart + (long long)blockIdx.z * M * N;
#pragma unroll
  for (int m = 0; m < 4; ++m) {
    int row0 = bm + (wr << 6) + (m << 4) + (lg << 2);
#pragma unroll
    for (int n = 0; n < 4; ++n) {
      int col = bn + (wc << 6) + (n << 4) + l15;
#pragma unroll
      for (int r = 0; r < 4; ++r) {
        Cp[(long long)(row0 + r) * N + col] = acc[m][n][r];
      }
    }
  }
}

// ---------------- split-K reduce + simple epilogue ----------------
// mode: 0 f32 (+bias if non-null) | 3 bf16 swish+bias | 4 bf16 gelu+bias
__global__ __launch_bounds__(256) void reduce_sk(
    const float* __restrict__ P, long long MN, int nsplit,
    const float* __restrict__ bias,
    void* __restrict__ out, int N, int ldout, int colbase, int mode) {
  long long i = ((long long)blockIdx.x * 256 + threadIdx.x) * 4;
  if (i >= MN) return;
  float4 acc = *(const float4*)&P[i];
  for (int s = 1; s < nsplit; ++s) {
    float4 p = *(const float4*)&P[s * MN + i];
    acc.x += p.x; acc.y += p.y; acc.z += p.z; acc.w += p.w;
  }
  int row = (int)(i / N), col = (int)(i % N);
  float v[4] = {acc.x, acc.y, acc.z, acc.w};
  if (bias) {
    float4 bv = *(const float4*)&bias[col];
    v[0] += bv.x; v[1] += bv.y; v[2] += bv.z; v[3] += bv.w;
  }
  long long oi = (long long)row * ldout + colbase + col;
  if (mode == 0) {
    *(float4*)&((float*)out)[oi] = make_float4(v[0], v[1], v[2], v[3]);
  } else if (mode == 3) {
    short4v o;
#pragma unroll
    for (int j = 0; j < 4; ++j)
      o[j] = (short)f2bf(v[j] / (1.0f + __expf(-1.702f * v[j])));
    *(short4v*)&((unsigned short*)out)[oi] = o;
  } else {
    short4v o;
#pragma unroll
    for (int j = 0; j < 4; ++j)
      o[j] = (short)f2bf(0.5f * v[j] * (1.0f + tanhf(0.79788456080286535588f *
                                                     (v[j] + 0.044715f * v[j] * v[j] * v[j]))));
    *(short4v*)&((unsigned short*)out)[oi] = o;
  }
}

// ---------------- split-K reduce + residual + LayerNorm fusion ----------------
// h_new = sum(partials) (+bias) (+res);  hout = h_new;  yout = LN(h_new)*g+b (bf16)
__global__ __launch_bounds__(256) void reduce_ln(
    const float* __restrict__ P, int nsplit,
    const float* __restrict__ bias, const float* __restrict__ res,
    const float* __restrict__ g, const float* __restrict__ b,
    float* __restrict__ hout, unsigned short* __restrict__ yout) {
  int r = blockIdx.x, tid = threadIdx.x;
  const float* prow = P + (long long)r * EMBED;
  const long long MN = (long long)SEQ * EMBED;
  __shared__ float r0[4], r1[4];
  float v[5];
  float s = 0.f, sq = 0.f;
#pragma unroll
  for (int i = 0; i < 5; ++i) {
    int col = tid + (i << 8);
    float x = bias ? bias[col] : 0.f;
    for (int z = 0; z < nsplit; ++z) x += prow[(long long)z * MN + col];
    if (res) x += res[(long long)r * EMBED + col];
    v[i] = x;
    s += x;
    sq += x * x;
  }
  float ws1 = waveReduceSum(s);
  float ws2 = waveReduceSum(sq);
  int lane = tid & 63, wid = tid >> 6;
  if (!lane) { r0[wid] = ws1; r1[wid] = ws2; }
  __syncthreads();
  s = r0[0] + r0[1] + r0[2] + r0[3];
  sq = r1[0] + r1[1] + r1[2] + r1[3];
  float mean = s * (1.0f / EMBED);
  float var = sq * (1.0f / EMBED) - mean * mean;
  float rstd = rsqrtf(var + 1e-6f);
  float* hrow = hout + (long long)r * EMBED;
  unsigned short* yrow = yout + (long long)r * EMBED;
#pragma unroll
  for (int i = 0; i < 5; ++i) {
    int col = tid + (i << 8);
    hrow[col] = v[i];
    yrow[col] = f2bf((v[i] - mean) * rstd * g[col] + b[col]);
  }
}

// ---------------- qkv split-K reduce + bias + RoPE + pack q/k/v ----------------
// qb,kb: [h][s][96] bf16 (q scaled), vtmp: [h][s][80] bf16 row-major
__global__ __launch_bounds__(256) void reduce_qkv(
    const float* __restrict__ P, int nsplit,
    const float* __restrict__ bias,
    const float* __restrict__ cosT, const float* __restrict__ sinT,
    unsigned short* __restrict__ qb, unsigned short* __restrict__ kb,
    unsigned short* __restrict__ vtmp, float qscale) {
  int s = blockIdx.x, tid = threadIdx.x;
  const long long MN = (long long)SEQ * QKV3;
  const float* prow = P + (long long)s * QKV3;
  // q,k with rope
  for (int idx = tid; idx < 640; idx += 256) {
    int hh = idx / 40, j = idx % 40;
    int cq = hh * 80 + j;
    float q0 = bias[cq], q1 = bias[cq + 40];
    float k0 = bias[1280 + cq], k1 = bias[1280 + cq + 40];
    for (int z = 0; z < nsplit; ++z) {
      const float* p = prow + (long long)z * MN;
      q0 += p[cq]; q1 += p[cq + 40];
      k0 += p[1280 + cq]; k1 += p[1280 + cq + 40];
    }
    float cs = cosT[s * 40 + j], sn = sinT[s * 40 + j];
    size_t o = ((size_t)hh * SEQ + s) * HDP;
    qb[o + j] = f2bf((q0 * cs - q1 * sn) * qscale);
    qb[o + j + 40] = f2bf((q1 * cs + q0 * sn) * qscale);
    kb[o + j] = f2bf(k0 * cs - k1 * sn);
    kb[o + j + 40] = f2bf(k1 * cs + k0 * sn);
  }
  // pad cols 80..95
  {
    int hh = tid >> 4, p = 80 + (tid & 15);
    size_t o = ((size_t)hh * SEQ + s) * HDP + p;
    qb[o] = 0;
    kb[o] = 0;
  }
  // v (row-major temp)
  for (int idx = tid; idx < 1280; idx += 256) {
    float v = bias[2560 + idx];
    for (int z = 0; z < nsplit; ++z) v += prow[(long long)z * MN + 2560 + idx];
    int hh = idx / 80, j = idx % 80;
    vtmp[((size_t)hh * SEQ + s) * 80 + j] = f2bf(v);
  }
}

// ---------------- transpose V: [h][s][80] bf16 -> [h][80][1024] bf16 ----------------
__global__ __launch_bounds__(256) void pack_v2(const unsigned short* __restrict__ vtmp,
                                               unsigned short* __restrict__ vb) {
  __shared__ unsigned short t[80][72];
  int hh = blockIdx.y, s0 = blockIdx.x << 6;
  int tid = threadIdx.x;
  int s = tid >> 2, c0 = (tid & 3) * 20;
  const unsigned short* src = vtmp + ((size_t)hh * SEQ + s0 + s) * 80 + c0;
#pragma unroll
  for (int j = 0; j < 20; ++j) t[c0 + j][s] = src[j];
  __syncthreads();
  unsigned short* dst = vb + (size_t)hh * 80 * SEQ + s0;
#pragma unroll
  for (int i = 0; i < 3; ++i) {
    int c = tid + (i << 8);
    if (c < 640) {
      int dr = c >> 3, col = (c & 7) << 3;
      *(short8*)&dst[(size_t)dr * SEQ + col] = *(const short8*)&t[dr][col];
    }
  }
}

// ---------------- fused flash attention ----------------
__global__ __launch_bounds__(256) void flash_attn(
    const unsigned short* __restrict__ qb,
    const unsigned short* __restrict__ kb,
    const unsigned short* __restrict__ vb,
    unsigned short* __restrict__ ob) {
  __shared__ short Ks[64 * 104];
  __shared__ short Vs[80 * 72];
  __shared__ short Ps[4 * 16 * 72];
  int h = blockIdx.y, q0 = blockIdx.x << 6;
  int tid = threadIdx.x, lane = tid & 63, wid = tid >> 6;
  int l15 = lane & 15, lg = lane >> 4;
  int kb8 = lg << 3;

  short8 qf[3];
  {
    const unsigned short* qrow = qb + ((size_t)h * SEQ + q0 + (wid << 4) + l15) * HDP;
#pragma unroll
    for (int dc = 0; dc < 3; ++dc) qf[dc] = *(const short8*)&qrow[dc * 32 + kb8];
  }

  f32x4 o_acc[5] = {};
  float m_run = -1e30f, l_run = 0.f;
  short* myP = &Ps[(wid * 16 + l15) * 72];

  for (int t = 0; t < 16; ++t) {
    int kv0 = t << 6;
    __syncthreads();
    {
      const unsigned short* gk = kb + ((size_t)h * SEQ + kv0) * HDP;
#pragma unroll
      for (int i = 0; i < 3; ++i) {
        int c = tid + (i << 8);
        int row = c / 12, col = (c % 12) << 3;
        *(short8*)&Ks[row * 104 + col] = *(const short8*)&gk[row * HDP + col];
      }
      const unsigned short* gv = vb + (size_t)h * 80 * SEQ + kv0;
#pragma unroll
      for (int i = 0; i < 3; ++i) {
        int c = tid + (i << 8);
        if (c < 640) {
          int row = c >> 3, col = (c & 7) << 3;
          *(short8*)&Vs[row * 72 + col] = *(const short8*)&gv[(size_t)row * SEQ + col];
        }
      }
    }
    __syncthreads();

    f32x4 s[4] = {};
#pragma unroll
    for (int ks = 0; ks < 4; ++ks) {
#pragma unroll
      for (int dc = 0; dc < 3; ++dc) {
        short8 kf = *(const short8*)&Ks[(ks * 16 + l15) * 104 + dc * 32 + kb8];
        s[ks] = __builtin_amdgcn_mfma_f32_16x16x32_bf16(kf, qf[dc], s[ks], 0, 0, 0);
      }
    }

    float mloc = -1e30f;
#pragma unroll
    for (int ks = 0; ks < 4; ++ks)
#pragma unroll
      for (int r = 0; r < 4; ++r) mloc = fmaxf(mloc, s[ks][r]);
    mloc = fmaxf(mloc, __shfl_xor(mloc, 16));
    mloc = fmaxf(mloc, __shfl_xor(mloc, 32));
    float m_new = fmaxf(m_run, mloc);
    float alpha = __expf(m_run - m_new);
    float psum = 0.f;
#pragma unroll
    for (int ks = 0; ks < 4; ++ks) {
      short4v pk;
#pragma unroll
      for (int r = 0; r < 4; ++r) {
        float p = __expf(s[ks][r] - m_new);
        psum += p;
        pk[r] = (short)f2bf(p);
      }
      *(short4v*)&myP[ks * 16 + (lg << 2)] = pk;
    }
    psum += __shfl_xor(psum, 16);
    psum += __shfl_xor(psum, 32);
    l_run = l_run * alpha + psum;
    m_run = m_new;
#pragma unroll
    for (int dt = 0; dt < 5; ++dt)
#pragma unroll
      for (int r = 0; r < 4; ++r) o_acc[dt][r] *= alpha;

#pragma unroll
    for (int dt = 0; dt < 5; ++dt) {
#pragma unroll
      for (int kc = 0; kc < 2; ++kc) {
        short8 vf = *(const short8*)&Vs[(dt * 16 + l15) * 72 + kc * 32 + kb8];
        short8 pf = *(const short8*)&myP[kc * 32 + kb8];
        o_acc[dt] = __builtin_amdgcn_mfma_f32_16x16x32_bf16(vf, pf, o_acc[dt], 0, 0, 0);
      }
    }
  }

  float inv = 1.0f / l_run;
  unsigned short* orow = ob + (size_t)(q0 + (wid << 4) + l15) * EMBED + h * HD;
#pragma unroll
  for (int dt = 0; dt < 5; ++dt) {
    short4v ov;
#pragma unroll
    for (int r = 0; r < 4; ++r) ov[r] = (short)f2bf(o_acc[dt][r] * inv);
    *(short4v*)&orow[dt * 16 + (lg << 2)] = ov;
  }
}

extern "C" void kernel_launch(void* const* d_in, const int* in_sizes, int n_in,
                              void* d_out, int out_size, void* d_ws, size_t ws_size,
                              hipStream_t stream) {
  const float* x = (const float*)d_in[0];
  const float* patch_w = (const float*)d_in[1];
  const float* ln1_g = (const float*)d_in[2];
  const float* ln1_b = (const float*)d_in[3];
  const float* qkv_w = (const float*)d_in[4];
  const float* qkv_b = (const float*)d_in[5];
  const float* proj_w = (const float*)d_in[6];
  const float* proj_b = (const float*)d_in[7];
  const float* ln2_g = (const float*)d_in[8];
  const float* ln2_b = (const float*)d_in[9];
  const float* fc1_w = (const float*)d_in[10];
  const float* fc1_b = (const float*)d_in[11];
  const float* fc2_w = (const float*)d_in[12];
  const float* fc2_b = (const float*)d_in[13];
  const float* mln_g = (const float*)d_in[14];
  const float* mln_b = (const float*)d_in[15];
  const float* mfc1_w = (const float*)d_in[16];
  const float* mfc1_b = (const float*)d_in[17];
  const float* mfc2_w = (const float*)d_in[18];
  const float* mfc2_b = (const float*)d_in[19];
  const int* grid_h = (const int*)d_in[21];
  const int* grid_w = (const int*)d_in[22];

  char* wsp = (char*)d_ws;
  char* ws0 = wsp;
  float* h = (float*)wsp;                       wsp += (size_t)SEQ * EMBED * 4;
  float* cosT = (float*)wsp;                    wsp += (size_t)SEQ * 40 * 4;
  float* sinT = (float*)wsp;                    wsp += (size_t)SEQ * 40 * 4;
  unsigned short* y = (unsigned short*)wsp;     wsp += (size_t)SEQ * EMBED * 2;
  unsigned short* ob = (unsigned short*)wsp;    wsp += (size_t)SEQ * EMBED * 2;
  unsigned short* m1b = (unsigned short*)wsp;   wsp += (size_t)MSEQ * MDIM * 2;
  unsigned short* qb = (unsigned short*)wsp;    wsp += (size_t)HEADS * SEQ * HDP * 2;
  unsigned short* kb = (unsigned short*)wsp;    wsp += (size_t)HEADS * SEQ * HDP * 2;
  unsigned short* vb = (unsigned short*)wsp;    wsp += (size_t)HEADS * HD * SEQ * 2;
  unsigned short* vtmp = (unsigned short*)wsp;  wsp += (size_t)HEADS * SEQ * HD * 2;
  unsigned short* u = (unsigned short*)wsp;     wsp += (size_t)SEQ * MLP_DIM * 2;
  unsigned short* xb = (unsigned short*)wsp;    wsp += (size_t)SEQ * PATCH_PAD * 2;
  unsigned short* wt = (unsigned short*)wsp;    wsp += (size_t)(MDIM / 2) * MDIM * 2;
  size_t fixed = (size_t)(wsp - ws0);

  // pre-transposed weight region (full path)
  const size_t E_QKV = (size_t)QKV3 * EMBED;    // per-layer elems
  const size_t E_PROJ = (size_t)EMBED * EMBED;
  const size_t E_FC1 = (size_t)MLP_DIM * EMBED;
  const size_t E_FC2 = (size_t)EMBED * MLP_DIM;
  const size_t E_PATCH = (size_t)EMBED * PATCH_PAD;
  const size_t E_M1 = (size_t)MDIM * MDIM;
  const size_t E_M2 = (size_t)HIDDEN * MDIM;
  size_t wregElems = DEPTH * (E_QKV + E_PROJ + E_FC1 + E_FC2) + E_PATCH + E_M1 + E_M2;
  size_t wregBytes = wregElems * 2;
  bool full = ws_size >= fixed + wregBytes + (size_t)66 * 1024 * 1024;

  unsigned short* wreg = (unsigned short*)wsp;
  unsigned short* Wq = wreg;
  unsigned short* Wp = Wq + DEPTH * E_QKV;
  unsigned short* Wf1 = Wp + DEPTH * E_PROJ;
  unsigned short* Wf2 = Wf1 + DEPTH * E_FC1;
  unsigned short* Wpa = Wf2 + DEPTH * E_FC2;
  unsigned short* Wm1 = Wpa + E_PATCH;
  unsigned short* Wm2 = Wm1 + E_M1;

  float* part = full ? (float*)(wsp + wregBytes) : (float*)wsp;
  size_t avail = ws_size - fixed - (full ? wregBytes : 0);

  auto splits_for = [&](long long MN, int want) {
    size_t one = (size_t)MN * 4;
    if (avail < one) return 1;
    long long cap = (long long)(avail / one);
    return (int)(want < cap ? want : cap);
  };
  auto chunk_for = [](int K, int s) { return ((K + s * 32 - 1) / (s * 32)) * 32; };

  const float scale = 1.0f / sqrtf(80.0f);
  dim3 blk(256);

  rope_tables_kernel<<<SEQ, 64, 0, stream>>>(grid_h, grid_w, cosT, sinT);
  convert_x<<<(SEQ * PATCH_PAD + 255) / 256, blk, 0, stream>>>(x, xb);

  if (full) {
    // batched upfront weight transposes (7 dispatches)
    transpose_w<<<dim3(PATCH_PAD / 32, EMBED / 32, 1), blk, 0, stream>>>(
        patch_w, EMBED, 0, Wpa, 0, PATCH_DIMS, PATCH_PAD);
    transpose_w<<<dim3(EMBED / 32, QKV3 / 32, DEPTH), blk, 0, stream>>>(
        qkv_w, QKV3, (long long)EMBED * QKV3, Wq, (long long)E_QKV, EMBED, EMBED);
    transpose_w<<<dim3(EMBED / 32, EMBED / 32, DEPTH), blk, 0, stream>>>(
        proj_w, EMBED, (long long)EMBED * EMBED, Wp, (long long)E_PROJ, EMBED, EMBED);
    transpose_w<<<dim3(EMBED / 32, MLP_DIM / 32, DEPTH), blk, 0, stream>>>(
        fc1_w, MLP_DIM, (long long)EMBED * MLP_DIM, Wf1, (long long)E_FC1, EMBED, EMBED);
    transpose_w<<<dim3(MLP_DIM / 32, EMBED / 32, DEPTH), blk, 0, stream>>>(
        fc2_w, EMBED, (long long)MLP_DIM * EMBED, Wf2, (long long)E_FC2, MLP_DIM, MLP_DIM);
    transpose_w<<<dim3(MDIM / 32, MDIM / 32, 1), blk, 0, stream>>>(
        mfc1_w, MDIM, 0, Wm1, 0, MDIM, MDIM);
    transpose_w<<<dim3(MDIM / 32, HIDDEN / 32, 1), blk, 0, stream>>>(
        mfc2_w, HIDDEN, 0, Wm2, 0, MDIM, MDIM);
  }

  // ---- patch embed + LN1(layer0): h = xb @ Wpa^T; y = LN ----
  {
    const unsigned short* W = Wpa;
    if (!full) {
      transpose_w<<<dim3(PATCH_PAD / 32, EMBED / 32, 1), blk, 0, stream>>>(
          patch_w, EMBED, 0, wt, 0, PATCH_DIMS, PATCH_PAD);
      W = wt;
    }
    long long MN = (long long)SEQ * EMBED;
    int s = splits_for(MN, 6), ch = chunk_for(PATCH_PAD, s);
    gemm_sk<<<dim3(EMBED / 128, SEQ / 128, s), blk, 0, stream>>>(
        xb, PATCH_PAD, W, PATCH_PAD, part, SEQ, EMBED, PATCH_PAD, ch);
    reduce_ln<<<SEQ, blk, 0, stream>>>(part, s, nullptr, nullptr,
                                       ln1_g, ln1_b, h, y);
  }

  for (int l = 0; l < DEPTH; ++l) {
    // qkv
    {
      const unsigned short* W = Wq + (size_t)l * E_QKV;
      if (!full) {
        transpose_w<<<dim3(EMBED / 32, QKV3 / 32, 1), blk, 0, stream>>>(
            qkv_w + (long long)l * EMBED * QKV3, QKV3, 0, wt, 0, EMBED, EMBED);
        W = wt;
      }
      long long MN = (long long)SEQ * QKV3;
      int s = splits_for(MN, 2), ch = chunk_for(EMBED, s);
      gemm_sk<<<dim3(QKV3 / 128, SEQ / 128, s), blk, 0, stream>>>(
          y, EMBED, W, EMBED, part, SEQ, QKV3, EMBED, ch);
      reduce_qkv<<<SEQ, blk, 0, stream>>>(part, s, qkv_b + l * QKV3,
                                          cosT, sinT, qb, kb, vtmp, scale);
    }
    pack_v2<<<dim3(16, HEADS), blk, 0, stream>>>(vtmp, vb);
    flash_attn<<<dim3(SEQ / 64, HEADS), blk, 0, stream>>>(qb, kb, vb, ob);
    // proj (+residual +LN2)
    {
      const unsigned short* W = Wp + (size_t)l * E_PROJ;
      if (!full) {
        transpose_w<<<dim3(EMBED / 32, EMBED / 32, 1), blk, 0, stream>>>(
            proj_w + (long long)l * EMBED * EMBED, EMBED, 0, wt, 0, EMBED, EMBED);
        W = wt;
      }
      long long MN = (long long)SEQ * EMBED;
      int s = splits_for(MN, 6), ch = chunk_for(EMBED, s);
      gemm_sk<<<dim3(EMBED / 128, SEQ / 128, s), blk, 0, stream>>>(
          ob, EMBED, W, EMBED, part, SEQ, EMBED, EMBED, ch);
      reduce_ln<<<SEQ, blk, 0, stream>>>(part, s, proj_b + l * EMBED, h,
                                         ln2_g + l * EMBED, ln2_b + l * EMBED, h, y);
    }
    // fc1 (swish)
    {
      const unsigned short* W = Wf1 + (size_t)l * E_FC1;
      if (!full) {
        transpose_w<<<dim3(EMBED / 32, MLP_DIM / 32, 1), blk, 0, stream>>>(
            fc1_w + (long long)l * EMBED * MLP_DIM, MLP_DIM, 0, wt, 0, EMBED, EMBED);
        W = wt;
      }
      long long MN = (long long)SEQ * MLP_DIM;
      int s = splits_for(MN, 2), ch = chunk_for(EMBED, s);
      gemm_sk<<<dim3(MLP_DIM / 128, SEQ / 128, s), blk, 0, stream>>>(
          y, EMBED, W, EMBED, part, SEQ, MLP_DIM, EMBED, ch);
      reduce_sk<<<(MN / 4 + 255) / 256, blk, 0, stream>>>(
          part, MN, s, fc1_b + l * MLP_DIM, u, MLP_DIM, MLP_DIM, 0, 3);
    }
    // fc2 (+residual +LN1-of-next / mln)
    {
      const unsigned short* W = Wf2 + (size_t)l * E_FC2;
      if (!full) {
        transpose_w<<<dim3(MLP_DIM / 32, EMBED / 32, 1), blk, 0, stream>>>(
            fc2_w + (long long)l * MLP_DIM * EMBED, EMBED, 0, wt, 0, MLP_DIM, MLP_DIM);
        W = wt;
      }
      long long MN = (long long)SEQ * EMBED;
      int s = splits_for(MN, 8), ch = chunk_for(MLP_DIM, s);
      gemm_sk<<<dim3(EMBED / 128, SEQ / 128, s), blk, 0, stream>>>(
          u, MLP_DIM, W, MLP_DIM, part, SEQ, EMBED, MLP_DIM, ch);
      const float* ng = (l < DEPTH - 1) ? ln1_g + (l + 1) * EMBED : mln_g;
      const float* nb = (l < DEPTH - 1) ? ln1_b + (l + 1) * EMBED : mln_b;
      reduce_ln<<<SEQ, blk, 0, stream>>>(part, s, fc2_b + l * EMBED, h, ng, nb, h, y);
    }
  }

  // ---- merger (y holds mln output, viewed as [256][5120]) ----
  if (full) {
    {
      long long MN = (long long)MSEQ * MDIM;
      int s = splits_for(MN, 12), ch = chunk_for(MDIM, s);
      gemm_sk<<<dim3(MDIM / 128, MSEQ / 128, s), blk, 0, stream>>>(
          y, MDIM, Wm1, MDIM, part, MSEQ, MDIM, MDIM, ch);
      reduce_sk<<<(MN / 4 + 255) / 256, blk, 0, stream>>>(
          part, MN, s, mfc1_b, m1b, MDIM, MDIM, 0, 4);
    }
    {
      long long MN = (long long)MSEQ * HIDDEN;
      int s = splits_for(MN, 12), ch = chunk_for(MDIM, s);
      gemm_sk<<<dim3(HIDDEN / 128, MSEQ / 128, s), blk, 0, stream>>>(
          m1b, MDIM, Wm2, MDIM, part, MSEQ, HIDDEN, MDIM, ch);
      reduce_sk<<<(MN / 4 + 255) / 256, blk, 0, stream>>>(
          part, MN, s, mfc2_b, (float*)d_out, HIDDEN, HIDDEN, 0, 0);
    }
  } else {
    for (int hh = 0; hh < 2; ++hh) {
      transpose_w<<<dim3(MDIM / 32, 2560 / 32, 1), blk, 0, stream>>>(
          mfc1_w + hh * 2560, MDIM, 0, wt, 0, MDIM, MDIM);
      long long MN = (long long)MSEQ * 2560;
      int s = splits_for(MN, 8), ch = chunk_for(MDIM, s);
      gemm_sk<<<dim3(2560 / 128, MSEQ / 128, s), blk, 0, stream>>>(
          y, MDIM, wt, MDIM, part, MSEQ, 2560, MDIM, ch);
      reduce_sk<<<(MN / 4 + 255) / 256, blk, 0, stream>>>(
          part, MN, s, mfc1_b + hh * 2560, m1b, 2560, MDIM, hh * 2560, 4);
    }
    for (int hh = 0; hh < 2; ++hh) {
      transpose_w<<<dim3(MDIM / 32, 1792 / 32, 1), blk, 0, stream>>>(
          mfc2_w + hh * 1792, HIDDEN, 0, wt, 0, MDIM, MDIM);
      long long MN = (long long)MSEQ * 1792;
      int s = splits_for(MN, 8), ch = chunk_for(MDIM, s);
      gemm_sk<<<dim3(1792 / 128, MSEQ / 128, s), blk, 0, stream>>>(
          m1b, MDIM, wt, MDIM, part, MSEQ, 1792, MDIM, ch);
      reduce_sk<<<(MN / 4 + 255) / 256, blk, 0, stream>>>(
          part, MN, s, mfc2_b + hh * 1792, (float*)d_out, 1792, HIDDEN, hh * 1792, 0);
    }
  }
}